// Round 16
// baseline (497.444 us; speedup 1.0000x reference)
//
#include <hip/hip_runtime.h>

#define Bn 8
#define Hn 8
#define Tn 1024
#define Dn 128

typedef __attribute__((ext_vector_type(8))) short bf16x8;
typedef __attribute__((ext_vector_type(4))) float f32x4;

typedef __attribute__((address_space(3))) unsigned int lds_as_t;
typedef __attribute__((address_space(1))) const unsigned int glb_as_t;

static __device__ __forceinline__ void gload_lds16(const unsigned short* g, unsigned short* l) {
    __builtin_amdgcn_global_load_lds((glb_as_t*)g, (lds_as_t*)l, 16, 0, 0);
}
static __device__ __forceinline__ void gload_lds16b(const char* g, char* l) {
    __builtin_amdgcn_global_load_lds((glb_as_t*)g, (lds_as_t*)l, 16, 0, 0);
}

static __device__ __forceinline__ unsigned short f2bf(float f) {
    union { float f; unsigned int u; } v; v.f = f;
    unsigned int u = v.u;
    return (unsigned short)((u + 0x7FFFu + ((u >> 16) & 1u)) >> 16);
}
static __device__ __forceinline__ int pack_bf16_trunc(float lo, float hi) {
    union { float f; unsigned int u; } a, b;
    a.f = lo; b.f = hi;
    return (int)__builtin_amdgcn_perm(b.u, a.u, 0x07060302u);
}

// Manual grid barrier: token-based, no init needed (robust to 0xAA poison / stale state).
// All 512 blocks are co-resident by construction (2 blocks/CU x 256 CUs), so spin is safe.
static __device__ __forceinline__ void grid_barrier(unsigned* flags, unsigned token) {
    __syncthreads();
    __threadfence();   // make this block's prior stores visible device-wide
    if (threadIdx.x == 0)
        __hip_atomic_store(&flags[blockIdx.x], token, __ATOMIC_RELEASE, __HIP_MEMORY_SCOPE_AGENT);
    const int i0 = threadIdx.x, i1 = threadIdx.x + 256;
    while (__hip_atomic_load(&flags[i0], __ATOMIC_ACQUIRE, __HIP_MEMORY_SCOPE_AGENT) != token)
        __builtin_amdgcn_s_sleep(1);
    while (__hip_atomic_load(&flags[i1], __ATOMIC_ACQUIRE, __HIP_MEMORY_SCOPE_AGENT) != token)
        __builtin_amdgcn_s_sleep(1);
    __syncthreads();
    __threadfence();
}

// ================= single kernel: prep -> qkv -> attn (persistent, manual grid sync) =================
__global__ __launch_bounds__(256, 2) void mega_kernel(
    const float* __restrict__ x,  const float* __restrict__ Wq,
    const float* __restrict__ Wk, const float* __restrict__ Wv,
    const float* __restrict__ Wu, const int* __restrict__ mask,
    const float* __restrict__ bu, float* __restrict__ out,
    unsigned short* __restrict__ xb,  unsigned short* __restrict__ wqB,
    unsigned short* __restrict__ wkB, unsigned short* __restrict__ wvB,
    unsigned short* __restrict__ wuF, char* __restrict__ Qf,
    char* __restrict__ Kf, unsigned short* __restrict__ Vtw,
    unsigned long long* __restrict__ mbits, unsigned* __restrict__ flags)
{
    __shared__ __align__(16) char shm[65536];   // union: qkv As|Bs (64K) / attn kbuf|vbuf (48K)

    const int gid  = blockIdx.x;      // 0..511
    const int tid  = threadIdx.x;
    const int wave = tid >> 6;
    const int lane = tid & 63;
    const int l16  = lane & 15;
    const int quad = lane >> 4;

    // ---------------- phase 0: prep (2816 virtual blocks over 512 real) ----------------
    for (int blk = gid; blk < 2816; blk += 512) {
        if (blk < 1408) {  // swizzled converts (16B chunk c ^= row&15)
            const float* in; unsigned short* o_; int i4;
            if (blk < 1024)      { in = x;  o_ = xb;  i4 = blk * 256 + tid; }
            else if (blk < 1152) { in = Wq; o_ = wqB; i4 = (blk - 1024) * 256 + tid; }
            else if (blk < 1280) { in = Wk; o_ = wkB; i4 = (blk - 1152) * 256 + tid; }
            else                 { in = Wv; o_ = wvB; i4 = (blk - 1280) * 256 + tid; }
            float4 f = ((const float4*)in)[i4];
            ushort4 o;
            o.x = f2bf(f.x); o.y = f2bf(f.y); o.z = f2bf(f.z); o.w = f2bf(f.w);
            int base = i4 * 4;
            int row = base >> 7, col = base & 127;
            int scol = (((col >> 3) ^ (row & 15)) << 3) | (col & 7);
            *(ushort4*)(o_ + row * 128 + scol) = o;
        } else if (blk < 1536) {  // Wu -> per-head fragment-major
            if (tid < 128) {
                int id = (blk - 1408) * 128 + tid;
                int lane_ = id & 63;
                int fid = id >> 6;               // ((h*4+ks)*8+nt)
                int nt = fid & 7, ks = (fid >> 3) & 3, h = fid >> 5;
                int row = nt * 16 + (lane_ & 15);
                int col = h * 128 + ks * 32 + (lane_ >> 4) * 8;
                const float* src = Wu + (size_t)row * 1024 + col;
                float4 f0 = *(const float4*)(src);
                float4 f1 = *(const float4*)(src + 4);
                unsigned short o[8];
                o[0] = f2bf(f0.x); o[1] = f2bf(f0.y); o[2] = f2bf(f0.z); o[3] = f2bf(f0.w);
                o[4] = f2bf(f1.x); o[5] = f2bf(f1.y); o[6] = f2bf(f1.z); o[7] = f2bf(f1.w);
                *(ushort4*)(wuF + (size_t)id * 8)     = *(ushort4*)&o[0];
                *(ushort4*)(wuF + (size_t)id * 8 + 4) = *(ushort4*)&o[4];
            }
        } else if (blk < 2560) {  // maskbits, transposed bits[kt*1024+row]
            int wid  = (blk - 1536) * 4 + (tid >> 6);
#pragma unroll
            for (int i = 0; i < 4; i++) {
                int widx = wid * 4 + i;
                int row = widx >> 4, kt = widx & 15;
                int v = mask[row * Tn + kt * 64 + lane];
                unsigned long long b = __ballot(v != 0);
                if (lane == 0) mbits[kt * Tn + row] = b;
            }
        } else {  // out preset = bias
            int f4 = (blk - 2560) * 1024 + tid * 4;
#pragma unroll
            for (int i = 0; i < 4; i++)
                ((float4*)out)[f4 + i] = ((const float4*)bu)[(f4 + i) & 31];
        }
    }

    grid_barrier(flags, 0x11111111u);

    // ---------------- phase 1: qkv (1536 items = 3 per block; R12 body) ----------------
    {
        unsigned short* As = (unsigned short*)shm;            // 32 KB
        unsigned short* Bs = (unsigned short*)(shm + 32768);  // 32 KB
        const int wm = wave & 1, wn = wave >> 1;

        for (int it = 0; it < 3; it++) {
            const int wi = gid + it * 512;
            const int bx = wi & 63, by = wi >> 6;
            __syncthreads();   // previous item fully done with LDS

            const int which = by >> 3;
            const unsigned short* wsel = (which == 0) ? wqB : (which == 1) ? wkB : wvB;
            const unsigned short* Ag = xb + (size_t)bx * 128 * 128;
            const unsigned short* Bg = wsel + (size_t)(by & 7) * 128 * 128;

#pragma unroll
            for (int i = 0; i < 8; i++) {
                int base = (wave * 8 + i) * 512;
                gload_lds16(Ag + base + lane * 8, &As[base]);
                gload_lds16(Bg + base + lane * 8, &Bs[base]);
            }
            __syncthreads();

            bf16x8 a[4][4];
#pragma unroll
            for (int mt = 0; mt < 4; mt++) {
                int row = wm * 64 + mt * 16 + l16;
#pragma unroll
                for (int ks = 0; ks < 4; ks++)
                    a[mt][ks] = *(const bf16x8*)(&As[row * 128 + (((ks * 4 + quad) ^ (row & 15)) << 3)]);
            }

            f32x4 acc[4][4];
#pragma unroll
            for (int nt = 0; nt < 4; nt++) {
                int row = wn * 64 + nt * 16 + l16;
                bf16x8 b4[4];
#pragma unroll
                for (int ks = 0; ks < 4; ks++)
                    b4[ks] = *(const bf16x8*)(&Bs[row * 128 + (((ks * 4 + quad) ^ (row & 15)) << 3)]);
#pragma unroll
                for (int mt = 0; mt < 4; mt++) {
                    f32x4 c = {0.f, 0.f, 0.f, 0.f};
#pragma unroll
                    for (int ks = 0; ks < 4; ks++)
                        c = __builtin_amdgcn_mfma_f32_16x16x32_bf16(a[mt][ks], b4[ks], c, 0, 0, 0);
                    acc[mt][nt] = c;
                }
            }

            const int h_ = by & 7;
            const int b_ = bx >> 3;
            if (which < 2) {
                __syncthreads();
                char* escr = shm;   // reuse As region
#pragma unroll
                for (int mt = 0; mt < 4; mt++) {
#pragma unroll
                    for (int nt = 0; nt < 4; nt++) {
                        int w = __builtin_amdgcn_cvt_pk_fp8_f32(acc[mt][nt][0], acc[mt][nt][1], 0, false);
                        w = __builtin_amdgcn_cvt_pk_fp8_f32(acc[mt][nt][2], acc[mt][nt][3], w, true);
                        int col = wn * 64 + nt * 16 + l16;
#pragma unroll
                        for (int r = 0; r < 4; r++)
                            escr[(wm * 64 + mt * 16 + quad * 4 + r) * 144 + col] = (char)(w >> (8 * r));
                    }
                }
                __syncthreads();
                int row = tid >> 1;
                int t_in = (bx & 7) * 128 + row;
                char* dst = (which == 0) ? Qf : Kf;
                size_t rowbase = ((size_t)((b_ * Hn + h_) * Tn + t_in)) * 128;
#pragma unroll
                for (int i = 0; i < 4; i++) {
                    int c = (tid & 1) * 4 + i;
                    int4 v = *(const int4*)(escr + row * 144 + c * 16);
                    int cc = (which == 1) ? (c ^ (row & 7)) : c;
                    *(int4*)(dst + rowbase + cc * 16) = v;
                }
            } else {
#pragma unroll
                for (int mt = 0; mt < 4; mt++) {
                    int m_base = bx * 128 + wm * 64 + mt * 16 + quad * 4;
                    int t0 = m_base & 1023;
#pragma unroll
                    for (int nt = 0; nt < 4; nt++) {
                        int e_ = wn * 64 + nt * 16 + l16;
                        int kt_ = t0 >> 6, tc0 = t0 & 63;
                        size_t off = ((((size_t)(b_ * Hn + h_) * 16 + kt_) * 128 + e_) << 6)
                                   + ((((tc0 >> 3) ^ (e_ & 7)) << 3) | (tc0 & 7));
                        ushort4 v4;
                        v4.x = f2bf(acc[mt][nt][0]); v4.y = f2bf(acc[mt][nt][1]);
                        v4.z = f2bf(acc[mt][nt][2]); v4.w = f2bf(acc[mt][nt][3]);
                        *(ushort4*)(Vtw + off) = v4;
                    }
                }
            }
        }
    }

    grid_barrier(flags, 0x22222222u);

    // ---------------- phase 2: attn (R14 body) + fused output projection ----------------
    {
        char* kb = shm;                                      // 2 x 8 KB
        unsigned short* vb = (unsigned short*)(shm + 16384); // 2 x 16 KB (8192 ushorts each)

        const int id   = gid;
        const int qb   = (id & 7) ^ (7 * ((id >> 8) & 1));
        const int bh   = (id >> 3) & 63;

        const char* Qb = Qf + (size_t)bh * Tn * Dn;
        const char* Kb = Kf + (size_t)bh * Tn * Dn;
        const unsigned short* Vb = Vtw + (size_t)bh * (16 * 128 * 64);

        const int blkkt = 2 * qb + 1;
        const int q0w   = qb * 128 + wave * 32;
        const int q0s[2] = { q0w, q0w + 16 };
        const int wkmax = (q0w + 31) >> 6;

        long qf[2][4];
#pragma unroll
        for (int st = 0; st < 2; st++)
#pragma unroll
            for (int ks = 0; ks < 4; ks++)
                qf[st][ks] = *(const long*)(Qb + (size_t)(q0s[st] + l16) * 128 + ks * 32 + quad * 8);

        bf16x8 ones;
#pragma unroll
        for (int j = 0; j < 8; j++) ones[j] = (short)0x3F80;

        f32x4 o[2][8];
#pragma unroll
        for (int st = 0; st < 2; st++)
#pragma unroll
            for (int et = 0; et < 8; et++) o[st][et] = (f32x4){0.f, 0.f, 0.f, 0.f};
        f32x4 lacc[2];
        lacc[0] = (f32x4){0.f, 0.f, 0.f, 0.f};
        lacc[1] = (f32x4){0.f, 0.f, 0.f, 0.f};

        const float SL = 0.12752041570284543f;  // 1/sqrt(128) * log2(e)

        const int idx0 = (l16 << 2) + ((quad & 1) << 7);
        const int idx1 = idx0 + 64;
        const bool hiQ = (quad >> 1) != 0;

#pragma unroll
        for (int i = 0; i < 2; i++) {
            int base = (wave * 2 + i) * 1024;
            gload_lds16b(Kb + base + lane * 16, &kb[base]);
        }
#pragma unroll
        for (int i = 0; i < 4; i++) {
            int base = (wave * 4 + i) * 512;
            gload_lds16(Vb + base + lane * 8, &vb[base]);
        }

        for (int kt = 0; kt <= blkkt; kt++) {
            const int cur = kt & 1;
            __syncthreads();

            if (kt < blkkt) {
                const char* Kg = Kb + (kt + 1) * (64 * 128);
                const unsigned short* Vg = Vb + (kt + 1) * (128 * 64);
#pragma unroll
                for (int i = 0; i < 2; i++) {
                    int base = (wave * 2 + i) * 1024;
                    gload_lds16b(Kg + base + lane * 16, &kb[(cur ^ 1) * 8192 + base]);
                }
#pragma unroll
                for (int i = 0; i < 4; i++) {
                    int base = (wave * 4 + i) * 512;
                    gload_lds16(Vg + base + lane * 8, &vb[(cur ^ 1) * 8192 + base]);
                }
            }

            if (kt <= wkmax) {
                unsigned long long mw[2];
                mw[0] = mbits[kt * Tn + q0s[0] + l16];
                mw[1] = mbits[kt * Tn + q0s[1] + l16];

                f32x4 s[2][4];
#pragma unroll
                for (int nt = 0; nt < 4; nt++) {
                    int row = nt * 16 + l16;
                    long a4[4];
#pragma unroll
                    for (int ks = 0; ks < 4; ks++) {
                        int c = ks * 2 + (quad >> 1);
                        a4[ks] = *(const long*)(&kb[cur * 8192 + row * 128 + (((c ^ (row & 7)) << 4) | ((quad & 1) << 3))]);
                    }
#pragma unroll
                    for (int st = 0; st < 2; st++) {
                        f32x4 c = {0.f, 0.f, 0.f, 0.f};
#pragma unroll
                        for (int ks = 0; ks < 4; ks++)
                            c = __builtin_amdgcn_mfma_f32_16x16x32_fp8_fp8(a4[ks], qf[st][ks], c, 0, 0, 0);
                        s[st][nt] = c;
                    }
                }

                const int kc0 = kt * 64;
                bf16x8 pf[2][2];
#pragma unroll
                for (int st = 0; st < 2; st++) {
                    const int qglob = q0s[st] + l16;
                    int w[4][2];
#pragma unroll
                    for (int nt = 0; nt < 4; nt++) {
                        float pv[4];
#pragma unroll
                        for (int r = 0; r < 4; r++) {
                            int bit = nt * 16 + quad * 4 + r;
                            bool live = ((mw[st] >> bit) & 1ULL) && (kc0 + bit <= qglob);
                            pv[r] = live ? __builtin_amdgcn_exp2f(s[st][nt][r] * SL) : 0.f;
                        }
                        w[nt][0] = pack_bf16_trunc(pv[0], pv[1]);
                        w[nt][1] = pack_bf16_trunc(pv[2], pv[3]);
                    }
#pragma unroll
                    for (int k2 = 0; k2 < 2; k2++) {
                        union { int i[4]; bf16x8 v; } u;
#pragma unroll
                        for (int d = 0; d < 4; d++) {
                            int idx = (d < 2) ? idx0 : idx1;
                            int va = __builtin_amdgcn_ds_bpermute(idx, w[2 * k2][d & 1]);
                            int vvb = __builtin_amdgcn_ds_bpermute(idx, w[2 * k2 + 1][d & 1]);
                            u.i[d] = hiQ ? vvb : va;
                        }
                        pf[st][k2] = u.v;
                    }
                }

#pragma unroll
                for (int st = 0; st < 2; st++)
#pragma unroll
                    for (int k2 = 0; k2 < 2; k2++)
                        lacc[st] = __builtin_amdgcn_mfma_f32_16x16x32_bf16(pf[st][k2], ones, lacc[st], 0, 0, 0);

#pragma unroll
                for (int et = 0; et < 8; et++) {
                    int row = et * 16 + l16;
#pragma unroll
                    for (int k2 = 0; k2 < 2; k2++) {
                        bf16x8 b = *(const bf16x8*)(&vb[cur * 8192 + row * 64 + (((k2 * 4 + quad) ^ (l16 & 7)) << 3)]);
                        o[0][et] = __builtin_amdgcn_mfma_f32_16x16x32_bf16(pf[0][k2], b, o[0][et], 0, 0, 0);
                        o[1][et] = __builtin_amdgcn_mfma_f32_16x16x32_bf16(pf[1][k2], b, o[1][et], 0, 0, 0);
                    }
                }
            }
        }

        // phase 2b: degenerate rows (l == 0) attend uniformly over all mask==0 keys
        __syncthreads();
        {
            bool deg = false;
#pragma unroll
            for (int st = 0; st < 2; st++)
#pragma unroll
                for (int r = 0; r < 4; r++) deg |= (lacc[st][r] == 0.f);
            if (__ballot(deg) != 0ULL) {
                unsigned short* pb = (unsigned short*)(shm + wave * 2304);  // 16 x 72 shorts
                unsigned short dsel[2][4];
#pragma unroll
                for (int st = 0; st < 2; st++)
#pragma unroll
                    for (int r = 0; r < 4; r++)
                        dsel[st][r] = (lacc[st][r] == 0.f) ? (unsigned short)0x3F80 : (unsigned short)0;
                for (int kt = 0; kt < 16; kt++) {
#pragma unroll
                    for (int st = 0; st < 2; st++) {
                        int qrow = q0s[st] + quad * 4;
                        unsigned long long mw2[4];
#pragma unroll
                        for (int r = 0; r < 4; r++) mw2[r] = mbits[kt * Tn + qrow + r];
#pragma unroll
                        for (int nt = 0; nt < 4; nt++) {
                            int bi = nt * 16 + l16;
#pragma unroll
                            for (int r = 0; r < 4; r++)
                                pb[(quad * 4 + r) * 72 + bi] = ((mw2[r] >> bi) & 1ULL) ? (unsigned short)0 : dsel[st][r];
                        }
                        bf16x8 pf[2];
#pragma unroll
                        for (int k2 = 0; k2 < 2; k2++)
                            pf[k2] = *(const bf16x8*)(&pb[l16 * 72 + k2 * 32 + quad * 8]);
#pragma unroll
                        for (int k2 = 0; k2 < 2; k2++)
                            lacc[st] = __builtin_amdgcn_mfma_f32_16x16x32_bf16(pf[k2], ones, lacc[st], 0, 0, 0);
                        const unsigned short* Vg = Vb + kt * (128 * 64);
#pragma unroll
                        for (int et = 0; et < 8; et++) {
#pragma unroll
                            for (int k2 = 0; k2 < 2; k2++) {
                                bf16x8 b = *(const bf16x8*)(Vg + (et * 16 + l16) * 64 + (((k2 * 4 + quad) ^ (l16 & 7)) << 3));
                                o[st][et] = __builtin_amdgcn_mfma_f32_16x16x32_bf16(pf[k2], b, o[st][et], 0, 0, 0);
                            }
                        }
                    }
                }
            }
        }

        // fused output projection epilogue
        const int b_ = bh >> 3, h_ = bh & 7;
        const unsigned short* wf = wuF + (size_t)h_ * (4 * 8 * 64 * 8);
#pragma unroll
        for (int st = 0; st < 2; st++) {
            unsigned short* tile = (unsigned short*)(shm + 16384 + wave * 4608);  // 16 x 144 shorts
#pragma unroll
            for (int r = 0; r < 4; r++) {
                float inv = 1.f / lacc[st][r];
                int row = quad * 4 + r;
#pragma unroll
                for (int et = 0; et < 8; et++)
                    tile[row * 144 + et * 16 + l16] = f2bf(o[st][et][r] * inv);
            }

            bf16x8 a4[4];
#pragma unroll
            for (int ks = 0; ks < 4; ks++)
                a4[ks] = *(const bf16x8*)(&tile[l16 * 144 + ks * 32 + quad * 8]);

            f32x4 acc2[8];
#pragma unroll
            for (int nt = 0; nt < 8; nt++) acc2[nt] = (f32x4){0.f, 0.f, 0.f, 0.f};
#pragma unroll
            for (int ks = 0; ks < 4; ks++) {
#pragma unroll
                for (int nt = 0; nt < 8; nt++) {
                    bf16x8 b = *(const bf16x8*)(wf + ((size_t)(ks * 8 + nt) * 64 + lane) * 8);
                    acc2[nt] = __builtin_amdgcn_mfma_f32_16x16x32_bf16(a4[ks], b, acc2[nt], 0, 0, 0);
                }
            }

#pragma unroll
            for (int nt = 0; nt < 8; nt++) {
                int n = nt * 16 + l16;
#pragma unroll
                for (int r = 0; r < 4; r++) {
                    int q = q0s[st] + quad * 4 + r;
                    atomicAdd(&out[(size_t)(b_ * Tn + q) * Dn + n], acc2[nt][r]);
                }
            }
        }
    }
}

extern "C" void kernel_launch(void* const* d_in, const int* in_sizes, int n_in,
                              void* d_out, int out_size, void* d_ws, size_t ws_size,
                              hipStream_t stream) {
    const float* x   = (const float*)d_in[0];
    const int* mask  = (const int*)d_in[1];
    const float* Wk  = (const float*)d_in[2];
    const float* Wq  = (const float*)d_in[3];
    const float* Wv  = (const float*)d_in[4];
    const float* Wu  = (const float*)d_in[5];
    const float* bu  = (const float*)d_in[6];
    float* out = (float*)d_out;

    char* ws = (char*)d_ws;
    unsigned short* xb  = (unsigned short*)ws; ws += (size_t)8192 * 128 * 2;
    unsigned short* wqB = (unsigned short*)ws; ws += (size_t)1024 * 128 * 2;
    unsigned short* wkB = (unsigned short*)ws; ws += (size_t)1024 * 128 * 2;
    unsigned short* wvB = (unsigned short*)ws; ws += (size_t)1024 * 128 * 2;
    unsigned short* wuF = (unsigned short*)ws; ws += (size_t)128 * 1024 * 2;
    char* Qf  = ws; ws += (size_t)64 * 1024 * 128;
    char* Kf  = ws; ws += (size_t)64 * 1024 * 128;
    unsigned short* Vtw = (unsigned short*)ws; ws += (size_t)64 * 1024 * 128 * 2;
    unsigned long long* mb = (unsigned long long*)ws; ws += (size_t)1024 * 16 * 8;
    unsigned* flags = (unsigned*)ws; ws += 512 * 4;

    mega_kernel<<<dim3(512), dim3(256), 0, stream>>>(
        x, Wq, Wk, Wv, Wu, mask, bu, out,
        xb, wqB, wkB, wvB, wuF, Qf, Kf, Vtw, mb, flags);
}

// Round 17
// 367.510 us; speedup vs baseline: 1.3536x; 1.3536x over previous
//
#include <hip/hip_runtime.h>

#define Bn 8
#define Hn 8
#define Tn 1024
#define Dn 128

typedef __attribute__((ext_vector_type(8))) short bf16x8;
typedef __attribute__((ext_vector_type(4))) float f32x4;

typedef __attribute__((address_space(3))) unsigned int lds_as_t;
typedef __attribute__((address_space(1))) const unsigned int glb_as_t;

static __device__ __forceinline__ void gload_lds16(const unsigned short* g, unsigned short* l) {
    __builtin_amdgcn_global_load_lds((glb_as_t*)g, (lds_as_t*)l, 16, 0, 0);
}
static __device__ __forceinline__ void gload_lds16b(const char* g, char* l) {
    __builtin_amdgcn_global_load_lds((glb_as_t*)g, (lds_as_t*)l, 16, 0, 0);
}

static __device__ __forceinline__ unsigned short f2bf(float f) {
    union { float f; unsigned int u; } v; v.f = f;
    unsigned int u = v.u;
    return (unsigned short)((u + 0x7FFFu + ((u >> 16) & 1u)) >> 16);
}
static __device__ __forceinline__ int pack_bf16_trunc(float lo, float hi) {
    union { float f; unsigned int u; } a, b;
    a.f = lo; b.f = hi;
    return (int)__builtin_amdgcn_perm(b.u, a.u, 0x07060302u);
}

// Two-stage grid barrier, token-based (no init; robust to 0xAA poison).
// Arrive: 1 writer+1 reader per flag. Gather: only block 0 polls (256 threads x 2 flags).
// Broadcast: single go-flag polled by one thread per block. All 512 blocks are
// co-resident by construction (64KB LDS, launch_bounds(256,2) -> 2 blocks/CU x 256 CU).
static __device__ __forceinline__ void grid_barrier(unsigned* flags, unsigned token) {
    __syncthreads();
    __threadfence();   // prior global stores visible device-wide before arrive
    if (threadIdx.x == 0)
        __hip_atomic_store(&flags[blockIdx.x], token, __ATOMIC_RELEASE, __HIP_MEMORY_SCOPE_AGENT);
    if (blockIdx.x == 0) {
        while (__hip_atomic_load(&flags[threadIdx.x], __ATOMIC_ACQUIRE, __HIP_MEMORY_SCOPE_AGENT) != token)
            __builtin_amdgcn_s_sleep(2);
        while (__hip_atomic_load(&flags[threadIdx.x + 256], __ATOMIC_ACQUIRE, __HIP_MEMORY_SCOPE_AGENT) != token)
            __builtin_amdgcn_s_sleep(2);
        __syncthreads();
        if (threadIdx.x == 0)
            __hip_atomic_store(&flags[512], token, __ATOMIC_RELEASE, __HIP_MEMORY_SCOPE_AGENT);
    } else {
        if (threadIdx.x == 0) {
            while (__hip_atomic_load(&flags[512], __ATOMIC_ACQUIRE, __HIP_MEMORY_SCOPE_AGENT) != token)
                __builtin_amdgcn_s_sleep(2);
        }
    }
    __syncthreads();
}

// ================= single kernel: prep -> qkv -> attn (persistent, manual grid sync) =================
__global__ __launch_bounds__(256, 2) void mega_kernel(
    const float* __restrict__ x,  const float* __restrict__ Wq,
    const float* __restrict__ Wk, const float* __restrict__ Wv,
    const float* __restrict__ Wu, const int* __restrict__ mask,
    const float* __restrict__ bu, float* __restrict__ out,
    unsigned short* __restrict__ xb,  unsigned short* __restrict__ wqB,
    unsigned short* __restrict__ wkB, unsigned short* __restrict__ wvB,
    unsigned short* __restrict__ wuF, char* __restrict__ Qf,
    char* __restrict__ Kf, unsigned short* __restrict__ Vtw,
    unsigned long long* __restrict__ mbits, unsigned* __restrict__ flags)
{
    __shared__ __align__(16) char shm[65536];   // union: qkv As|Bs (64K) / attn kbuf|vbuf (48K)

    const int gid  = blockIdx.x;      // 0..511
    const int tid  = threadIdx.x;
    const int wave = tid >> 6;
    const int lane = tid & 63;
    const int l16  = lane & 15;
    const int quad = lane >> 4;

    // ---------------- phase 0: prep (2816 virtual blocks over 512 real) ----------------
    for (int blk = gid; blk < 2816; blk += 512) {
        if (blk < 1408) {  // swizzled converts (16B chunk c ^= row&15)
            const float* in; unsigned short* o_; int i4;
            if (blk < 1024)      { in = x;  o_ = xb;  i4 = blk * 256 + tid; }
            else if (blk < 1152) { in = Wq; o_ = wqB; i4 = (blk - 1024) * 256 + tid; }
            else if (blk < 1280) { in = Wk; o_ = wkB; i4 = (blk - 1152) * 256 + tid; }
            else                 { in = Wv; o_ = wvB; i4 = (blk - 1280) * 256 + tid; }
            float4 f = ((const float4*)in)[i4];
            ushort4 o;
            o.x = f2bf(f.x); o.y = f2bf(f.y); o.z = f2bf(f.z); o.w = f2bf(f.w);
            int base = i4 * 4;
            int row = base >> 7, col = base & 127;
            int scol = (((col >> 3) ^ (row & 15)) << 3) | (col & 7);
            *(ushort4*)(o_ + row * 128 + scol) = o;
        } else if (blk < 1536) {  // Wu -> per-head fragment-major
            if (tid < 128) {
                int id = (blk - 1408) * 128 + tid;
                int lane_ = id & 63;
                int fid = id >> 6;               // ((h*4+ks)*8+nt)
                int nt = fid & 7, ks = (fid >> 3) & 3, h = fid >> 5;
                int row = nt * 16 + (lane_ & 15);
                int col = h * 128 + ks * 32 + (lane_ >> 4) * 8;
                const float* src = Wu + (size_t)row * 1024 + col;
                float4 f0 = *(const float4*)(src);
                float4 f1 = *(const float4*)(src + 4);
                unsigned short o[8];
                o[0] = f2bf(f0.x); o[1] = f2bf(f0.y); o[2] = f2bf(f0.z); o[3] = f2bf(f0.w);
                o[4] = f2bf(f1.x); o[5] = f2bf(f1.y); o[6] = f2bf(f1.z); o[7] = f2bf(f1.w);
                *(ushort4*)(wuF + (size_t)id * 8)     = *(ushort4*)&o[0];
                *(ushort4*)(wuF + (size_t)id * 8 + 4) = *(ushort4*)&o[4];
            }
        } else if (blk < 2560) {  // maskbits, transposed bits[kt*1024+row]
            int wid  = (blk - 1536) * 4 + (tid >> 6);
#pragma unroll
            for (int i = 0; i < 4; i++) {
                int widx = wid * 4 + i;
                int row = widx >> 4, kt = widx & 15;
                int v = mask[row * Tn + kt * 64 + lane];
                unsigned long long b = __ballot(v != 0);
                if (lane == 0) mbits[kt * Tn + row] = b;
            }
        } else {  // out preset = bias
            int f4 = (blk - 2560) * 1024 + tid * 4;
#pragma unroll
            for (int i = 0; i < 4; i++)
                ((float4*)out)[f4 + i] = ((const float4*)bu)[(f4 + i) & 31];
        }
    }

    grid_barrier(flags, 0x11111111u);

    // ---------------- phase 1: qkv (1536 items = 3 per block; R12 body) ----------------
    {
        unsigned short* As = (unsigned short*)shm;            // 32 KB
        unsigned short* Bs = (unsigned short*)(shm + 32768);  // 32 KB
        const int wm = wave & 1, wn = wave >> 1;

        for (int it = 0; it < 3; it++) {
            const int wi = gid + it * 512;
            const int bx = wi & 63, by = wi >> 6;
            __syncthreads();   // previous item fully done with LDS

            const int which = by >> 3;
            const unsigned short* wsel = (which == 0) ? wqB : (which == 1) ? wkB : wvB;
            const unsigned short* Ag = xb + (size_t)bx * 128 * 128;
            const unsigned short* Bg = wsel + (size_t)(by & 7) * 128 * 128;

#pragma unroll
            for (int i = 0; i < 8; i++) {
                int base = (wave * 8 + i) * 512;
                gload_lds16(Ag + base + lane * 8, &As[base]);
                gload_lds16(Bg + base + lane * 8, &Bs[base]);
            }
            __syncthreads();

            bf16x8 a[4][4];
#pragma unroll
            for (int mt = 0; mt < 4; mt++) {
                int row = wm * 64 + mt * 16 + l16;
#pragma unroll
                for (int ks = 0; ks < 4; ks++)
                    a[mt][ks] = *(const bf16x8*)(&As[row * 128 + (((ks * 4 + quad) ^ (row & 15)) << 3)]);
            }

            f32x4 acc[4][4];
#pragma unroll
            for (int nt = 0; nt < 4; nt++) {
                int row = wn * 64 + nt * 16 + l16;
                bf16x8 b4[4];
#pragma unroll
                for (int ks = 0; ks < 4; ks++)
                    b4[ks] = *(const bf16x8*)(&Bs[row * 128 + (((ks * 4 + quad) ^ (row & 15)) << 3)]);
#pragma unroll
                for (int mt = 0; mt < 4; mt++) {
                    f32x4 c = {0.f, 0.f, 0.f, 0.f};
#pragma unroll
                    for (int ks = 0; ks < 4; ks++)
                        c = __builtin_amdgcn_mfma_f32_16x16x32_bf16(a[mt][ks], b4[ks], c, 0, 0, 0);
                    acc[mt][nt] = c;
                }
            }

            const int h_ = by & 7;
            const int b_ = bx >> 3;
            if (which < 2) {
                __syncthreads();
                char* escr = shm;   // reuse As region
#pragma unroll
                for (int mt = 0; mt < 4; mt++) {
#pragma unroll
                    for (int nt = 0; nt < 4; nt++) {
                        int w = __builtin_amdgcn_cvt_pk_fp8_f32(acc[mt][nt][0], acc[mt][nt][1], 0, false);
                        w = __builtin_amdgcn_cvt_pk_fp8_f32(acc[mt][nt][2], acc[mt][nt][3], w, true);
                        int col = wn * 64 + nt * 16 + l16;
#pragma unroll
                        for (int r = 0; r < 4; r++)
                            escr[(wm * 64 + mt * 16 + quad * 4 + r) * 144 + col] = (char)(w >> (8 * r));
                    }
                }
                __syncthreads();
                int row = tid >> 1;
                int t_in = (bx & 7) * 128 + row;
                char* dst = (which == 0) ? Qf : Kf;
                size_t rowbase = ((size_t)((b_ * Hn + h_) * Tn + t_in)) * 128;
#pragma unroll
                for (int i = 0; i < 4; i++) {
                    int c = (tid & 1) * 4 + i;
                    int4 v = *(const int4*)(escr + row * 144 + c * 16);
                    int cc = (which == 1) ? (c ^ (row & 7)) : c;
                    *(int4*)(dst + rowbase + cc * 16) = v;
                }
            } else {
#pragma unroll
                for (int mt = 0; mt < 4; mt++) {
                    int m_base = bx * 128 + wm * 64 + mt * 16 + quad * 4;
                    int t0 = m_base & 1023;
#pragma unroll
                    for (int nt = 0; nt < 4; nt++) {
                        int e_ = wn * 64 + nt * 16 + l16;
                        int kt_ = t0 >> 6, tc0 = t0 & 63;
                        size_t off = ((((size_t)(b_ * Hn + h_) * 16 + kt_) * 128 + e_) << 6)
                                   + ((((tc0 >> 3) ^ (e_ & 7)) << 3) | (tc0 & 7));
                        ushort4 v4;
                        v4.x = f2bf(acc[mt][nt][0]); v4.y = f2bf(acc[mt][nt][1]);
                        v4.z = f2bf(acc[mt][nt][2]); v4.w = f2bf(acc[mt][nt][3]);
                        *(ushort4*)(Vtw + off) = v4;
                    }
                }
            }
        }
    }

    grid_barrier(flags, 0x22222222u);

    // ---------------- phase 2: attn (R14 body) + fused output projection ----------------
    {
        char* kb = shm;                                      // 2 x 8 KB
        unsigned short* vb = (unsigned short*)(shm + 16384); // 2 x 16 KB (8192 ushorts each)

        const int id   = gid;
        const int qb   = (id & 7) ^ (7 * ((id >> 8) & 1));
        const int bh   = (id >> 3) & 63;

        const char* Qb = Qf + (size_t)bh * Tn * Dn;
        const char* Kb = Kf + (size_t)bh * Tn * Dn;
        const unsigned short* Vb = Vtw + (size_t)bh * (16 * 128 * 64);

        const int blkkt = 2 * qb + 1;
        const int q0w   = qb * 128 + wave * 32;
        const int q0s[2] = { q0w, q0w + 16 };
        const int wkmax = (q0w + 31) >> 6;

        long qf[2][4];
#pragma unroll
        for (int st = 0; st < 2; st++)
#pragma unroll
            for (int ks = 0; ks < 4; ks++)
                qf[st][ks] = *(const long*)(Qb + (size_t)(q0s[st] + l16) * 128 + ks * 32 + quad * 8);

        bf16x8 ones;
#pragma unroll
        for (int j = 0; j < 8; j++) ones[j] = (short)0x3F80;

        f32x4 o[2][8];
#pragma unroll
        for (int st = 0; st < 2; st++)
#pragma unroll
            for (int et = 0; et < 8; et++) o[st][et] = (f32x4){0.f, 0.f, 0.f, 0.f};
        f32x4 lacc[2];
        lacc[0] = (f32x4){0.f, 0.f, 0.f, 0.f};
        lacc[1] = (f32x4){0.f, 0.f, 0.f, 0.f};

        const float SL = 0.12752041570284543f;  // 1/sqrt(128) * log2(e)

        const int idx0 = (l16 << 2) + ((quad & 1) << 7);
        const int idx1 = idx0 + 64;
        const bool hiQ = (quad >> 1) != 0;

#pragma unroll
        for (int i = 0; i < 2; i++) {
            int base = (wave * 2 + i) * 1024;
            gload_lds16b(Kb + base + lane * 16, &kb[base]);
        }
#pragma unroll
        for (int i = 0; i < 4; i++) {
            int base = (wave * 4 + i) * 512;
            gload_lds16(Vb + base + lane * 8, &vb[base]);
        }

        for (int kt = 0; kt <= blkkt; kt++) {
            const int cur = kt & 1;
            __syncthreads();

            if (kt < blkkt) {
                const char* Kg = Kb + (kt + 1) * (64 * 128);
                const unsigned short* Vg = Vb + (kt + 1) * (128 * 64);
#pragma unroll
                for (int i = 0; i < 2; i++) {
                    int base = (wave * 2 + i) * 1024;
                    gload_lds16b(Kg + base + lane * 16, &kb[(cur ^ 1) * 8192 + base]);
                }
#pragma unroll
                for (int i = 0; i < 4; i++) {
                    int base = (wave * 4 + i) * 512;
                    gload_lds16(Vg + base + lane * 8, &vb[(cur ^ 1) * 8192 + base]);
                }
            }

            if (kt <= wkmax) {
                unsigned long long mw[2];
                mw[0] = mbits[kt * Tn + q0s[0] + l16];
                mw[1] = mbits[kt * Tn + q0s[1] + l16];

                f32x4 s[2][4];
#pragma unroll
                for (int nt = 0; nt < 4; nt++) {
                    int row = nt * 16 + l16;
                    long a4[4];
#pragma unroll
                    for (int ks = 0; ks < 4; ks++) {
                        int c = ks * 2 + (quad >> 1);
                        a4[ks] = *(const long*)(&kb[cur * 8192 + row * 128 + (((c ^ (row & 7)) << 4) | ((quad & 1) << 3))]);
                    }
#pragma unroll
                    for (int st = 0; st < 2; st++) {
                        f32x4 c = {0.f, 0.f, 0.f, 0.f};
#pragma unroll
                        for (int ks = 0; ks < 4; ks++)
                            c = __builtin_amdgcn_mfma_f32_16x16x32_fp8_fp8(a4[ks], qf[st][ks], c, 0, 0, 0);
                        s[st][nt] = c;
                    }
                }

                const int kc0 = kt * 64;
                bf16x8 pf[2][2];
#pragma unroll
                for (int st = 0; st < 2; st++) {
                    const int qglob = q0s[st] + l16;
                    int w[4][2];
#pragma unroll
                    for (int nt = 0; nt < 4; nt++) {
                        float pv[4];
#pragma unroll
                        for (int r = 0; r < 4; r++) {
                            int bit = nt * 16 + quad * 4 + r;
                            bool live = ((mw[st] >> bit) & 1ULL) && (kc0 + bit <= qglob);
                            pv[r] = live ? __builtin_amdgcn_exp2f(s[st][nt][r] * SL) : 0.f;
                        }
                        w[nt][0] = pack_bf16_trunc(pv[0], pv[1]);
                        w[nt][1] = pack_bf16_trunc(pv[2], pv[3]);
                    }
#pragma unroll
                    for (int k2 = 0; k2 < 2; k2++) {
                        union { int i[4]; bf16x8 v; } u;
#pragma unroll
                        for (int d = 0; d < 4; d++) {
                            int idx = (d < 2) ? idx0 : idx1;
                            int va = __builtin_amdgcn_ds_bpermute(idx, w[2 * k2][d & 1]);
                            int vvb = __builtin_amdgcn_ds_bpermute(idx, w[2 * k2 + 1][d & 1]);
                            u.i[d] = hiQ ? vvb : va;
                        }
                        pf[st][k2] = u.v;
                    }
                }

#pragma unroll
                for (int st = 0; st < 2; st++)
#pragma unroll
                    for (int k2 = 0; k2 < 2; k2++)
                        lacc[st] = __builtin_amdgcn_mfma_f32_16x16x32_bf16(pf[st][k2], ones, lacc[st], 0, 0, 0);

#pragma unroll
                for (int et = 0; et < 8; et++) {
                    int row = et * 16 + l16;
#pragma unroll
                    for (int k2 = 0; k2 < 2; k2++) {
                        bf16x8 b = *(const bf16x8*)(&vb[cur * 8192 + row * 64 + (((k2 * 4 + quad) ^ (l16 & 7)) << 3)]);
                        o[0][et] = __builtin_amdgcn_mfma_f32_16x16x32_bf16(pf[0][k2], b, o[0][et], 0, 0, 0);
                        o[1][et] = __builtin_amdgcn_mfma_f32_16x16x32_bf16(pf[1][k2], b, o[1][et], 0, 0, 0);
                    }
                }
            }
        }

        // phase 2b: degenerate rows (l == 0) attend uniformly over all mask==0 keys
        __syncthreads();
        {
            bool deg = false;
#pragma unroll
            for (int st = 0; st < 2; st++)
#pragma unroll
                for (int r = 0; r < 4; r++) deg |= (lacc[st][r] == 0.f);
            if (__ballot(deg) != 0ULL) {
                unsigned short* pb = (unsigned short*)(shm + wave * 2304);  // 16 x 72 shorts
                unsigned short dsel[2][4];
#pragma unroll
                for (int st = 0; st < 2; st++)
#pragma unroll
                    for (int r = 0; r < 4; r++)
                        dsel[st][r] = (lacc[st][r] == 0.f) ? (unsigned short)0x3F80 : (unsigned short)0;
                for (int kt = 0; kt < 16; kt++) {
#pragma unroll
                    for (int st = 0; st < 2; st++) {
                        int qrow = q0s[st] + quad * 4;
                        unsigned long long mw2[4];
#pragma unroll
                        for (int r = 0; r < 4; r++) mw2[r] = mbits[kt * Tn + qrow + r];
#pragma unroll
                        for (int nt = 0; nt < 4; nt++) {
                            int bi = nt * 16 + l16;
#pragma unroll
                            for (int r = 0; r < 4; r++)
                                pb[(quad * 4 + r) * 72 + bi] = ((mw2[r] >> bi) & 1ULL) ? (unsigned short)0 : dsel[st][r];
                        }
                        bf16x8 pf[2];
#pragma unroll
                        for (int k2 = 0; k2 < 2; k2++)
                            pf[k2] = *(const bf16x8*)(&pb[l16 * 72 + k2 * 32 + quad * 8]);
#pragma unroll
                        for (int k2 = 0; k2 < 2; k2++)
                            lacc[st] = __builtin_amdgcn_mfma_f32_16x16x32_bf16(pf[k2], ones, lacc[st], 0, 0, 0);
                        const unsigned short* Vg = Vb + kt * (128 * 64);
#pragma unroll
                        for (int et = 0; et < 8; et++) {
#pragma unroll
                            for (int k2 = 0; k2 < 2; k2++) {
                                bf16x8 b = *(const bf16x8*)(Vg + (et * 16 + l16) * 64 + (((k2 * 4 + quad) ^ (l16 & 7)) << 3));
                                o[st][et] = __builtin_amdgcn_mfma_f32_16x16x32_bf16(pf[k2], b, o[st][et], 0, 0, 0);
                            }
                        }
                    }
                }
            }
        }

        // fused output projection epilogue
        const int b_ = bh >> 3, h_ = bh & 7;
        const unsigned short* wf = wuF + (size_t)h_ * (4 * 8 * 64 * 8);
#pragma unroll
        for (int st = 0; st < 2; st++) {
            unsigned short* tile = (unsigned short*)(shm + 16384 + wave * 4608);  // 16 x 144 shorts
#pragma unroll
            for (int r = 0; r < 4; r++) {
                float inv = 1.f / lacc[st][r];
                int row = quad * 4 + r;
#pragma unroll
                for (int et = 0; et < 8; et++)
                    tile[row * 144 + et * 16 + l16] = f2bf(o[st][et][r] * inv);
            }

            bf16x8 a4[4];
#pragma unroll
            for (int ks = 0; ks < 4; ks++)
                a4[ks] = *(const bf16x8*)(&tile[l16 * 144 + ks * 32 + quad * 8]);

            f32x4 acc2[8];
#pragma unroll
            for (int nt = 0; nt < 8; nt++) acc2[nt] = (f32x4){0.f, 0.f, 0.f, 0.f};
#pragma unroll
            for (int ks = 0; ks < 4; ks++) {
#pragma unroll
                for (int nt = 0; nt < 8; nt++) {
                    bf16x8 b = *(const bf16x8*)(wf + ((size_t)(ks * 8 + nt) * 64 + lane) * 8);
                    acc2[nt] = __builtin_amdgcn_mfma_f32_16x16x32_bf16(a4[ks], b, acc2[nt], 0, 0, 0);
                }
            }

#pragma unroll
            for (int nt = 0; nt < 8; nt++) {
                int n = nt * 16 + l16;
#pragma unroll
                for (int r = 0; r < 4; r++) {
                    int q = q0s[st] + quad * 4 + r;
                    atomicAdd(&out[(size_t)(b_ * Tn + q) * Dn + n], acc2[nt][r]);
                }
            }
        }
    }
}

extern "C" void kernel_launch(void* const* d_in, const int* in_sizes, int n_in,
                              void* d_out, int out_size, void* d_ws, size_t ws_size,
                              hipStream_t stream) {
    const float* x   = (const float*)d_in[0];
    const int* mask  = (const int*)d_in[1];
    const float* Wk  = (const float*)d_in[2];
    const float* Wq  = (const float*)d_in[3];
    const float* Wv  = (const float*)d_in[4];
    const float* Wu  = (const float*)d_in[5];
    const float* bu  = (const float*)d_in[6];
    float* out = (float*)d_out;

    char* ws = (char*)d_ws;
    unsigned short* xb  = (unsigned short*)ws; ws += (size_t)8192 * 128 * 2;
    unsigned short* wqB = (unsigned short*)ws; ws += (size_t)1024 * 128 * 2;
    unsigned short* wkB = (unsigned short*)ws; ws += (size_t)1024 * 128 * 2;
    unsigned short* wvB = (unsigned short*)ws; ws += (size_t)1024 * 128 * 2;
    unsigned short* wuF = (unsigned short*)ws; ws += (size_t)128 * 1024 * 2;
    char* Qf  = ws; ws += (size_t)64 * 1024 * 128;
    char* Kf  = ws; ws += (size_t)64 * 1024 * 128;
    unsigned short* Vtw = (unsigned short*)ws; ws += (size_t)64 * 1024 * 128 * 2;
    unsigned long long* mb = (unsigned long long*)ws; ws += (size_t)1024 * 16 * 8;
    unsigned* flags = (unsigned*)ws; ws += 1024 * 4;

    mega_kernel<<<dim3(512), dim3(256), 0, stream>>>(
        x, Wq, Wk, Wv, Wu, mask, bu, out,
        xb, wqB, wkB, wvB, wuF, Qf, Kf, Vtw, mb, flags);
}

// Round 18
// 158.211 us; speedup vs baseline: 3.1442x; 2.3229x over previous
//
#include <hip/hip_runtime.h>

#define Bn 8
#define Hn 8
#define Tn 1024
#define Dn 128

typedef __attribute__((ext_vector_type(8))) short bf16x8;
typedef __attribute__((ext_vector_type(4))) float f32x4;

typedef __attribute__((address_space(3))) unsigned int lds_as_t;
typedef __attribute__((address_space(1))) const unsigned int glb_as_t;

static __device__ __forceinline__ void gload_lds16(const unsigned short* g, unsigned short* l) {
    __builtin_amdgcn_global_load_lds((glb_as_t*)g, (lds_as_t*)l, 16, 0, 0);
}
static __device__ __forceinline__ void gload_lds16b(const char* g, char* l) {
    __builtin_amdgcn_global_load_lds((glb_as_t*)g, (lds_as_t*)l, 16, 0, 0);
}

static __device__ __forceinline__ unsigned short f2bf(float f) {
    union { float f; unsigned int u; } v; v.f = f;
    unsigned int u = v.u;
    return (unsigned short)((u + 0x7FFFu + ((u >> 16) & 1u)) >> 16);
}
static __device__ __forceinline__ int pack_bf16_trunc(float lo, float hi) {
    union { float f; unsigned int u; } a, b;
    a.f = lo; b.f = hi;
    return (int)__builtin_amdgcn_perm(b.u, a.u, 0x07060302u);
}

// ---------------- dispatch 1: fused prep + QKV GEMM ----------------
// grid (64, 24): which = by>>3 in {Q,K,V}; head = by&7; m-tile = bx.
// Inline staging: fp32 A-tile (x) and B-slice (W) loaded directly, converted in
// registers, written to LDS in the swizzled image (chunk c at ((c^(row&15))<<3)).
// Side work (before staging): which==0 -> mask bitpack; which==1 -> wuF reorder;
// which==2 -> out = bias preset (target of attn's atomic accumulation).
__global__ __launch_bounds__(256, 2) void qkv_kernel(
    const float* __restrict__ x,  const float* __restrict__ Wq,
    const float* __restrict__ Wk, const float* __restrict__ Wv,
    const float* __restrict__ Wu, const int* __restrict__ mask,
    const float* __restrict__ bu, float* __restrict__ out,
    unsigned short* __restrict__ wuF, unsigned long long* __restrict__ mbits,
    char* __restrict__ Q, char* __restrict__ K, unsigned short* __restrict__ Vt)
{
    const int bx = blockIdx.x, by = blockIdx.y;
    const int tid  = threadIdx.x;
    const int wave = tid >> 6;
    const int lane = tid & 63;
    const int l16  = lane & 15;
    const int quad = lane >> 4;
    const int wm = wave & 1, wn = wave >> 1;
    const int which = by >> 3;
    const int h_ = by & 7;
    const int bid = h_ * 64 + bx;          // 0..511 within this 'which' group

    __shared__ __align__(16) unsigned short As[128 * 128];
    __shared__ __align__(16) unsigned short Bs[128 * 128];

    // ---- side work (independent of the GEMM; consumed by dispatch 2) ----
    if (which == 0) {
        // mask -> bits[kt*1024 + row], 16384 words over 512 blocks x 4 waves x 8
        int base = (bid * 4 + wave) * 8;
#pragma unroll
        for (int i = 0; i < 8; i++) {
            int widx = base + i;
            int row = widx >> 4, kt = widx & 15;
            int v = mask[row * Tn + kt * 64 + lane];
            unsigned long long b = __ballot(v != 0);
            if (lane == 0) mbits[kt * Tn + row] = b;
        }
    } else if (which == 1) {
        // Wu -> per-head fragment-major wuF, 16384 entries over 512 blocks x 32 threads
        if (tid < 32) {
            int id = bid * 32 + tid;
            int lane_ = id & 63;
            int fid = id >> 6;               // ((h*4+ks)*8+nt)
            int nt = fid & 7, ks = (fid >> 3) & 3, h = fid >> 5;
            int row = nt * 16 + (lane_ & 15);
            int col = h * 128 + ks * 32 + (lane_ >> 4) * 8;
            const float* src = Wu + (size_t)row * 1024 + col;
            float4 f0 = *(const float4*)(src);
            float4 f1 = *(const float4*)(src + 4);
            unsigned short o[8];
            o[0] = f2bf(f0.x); o[1] = f2bf(f0.y); o[2] = f2bf(f0.z); o[3] = f2bf(f0.w);
            o[4] = f2bf(f1.x); o[5] = f2bf(f1.y); o[6] = f2bf(f1.z); o[7] = f2bf(f1.w);
            *(ushort4*)(wuF + (size_t)id * 8)     = *(ushort4*)&o[0];
            *(ushort4*)(wuF + (size_t)id * 8 + 4) = *(ushort4*)&o[4];
        }
    } else {
        // out preset = bias broadcast (262144 float4 over 512 blocks x 256 threads x 2)
        int f4 = bid * 512 + tid * 2;
#pragma unroll
        for (int i = 0; i < 2; i++)
            ((float4*)out)[f4 + i] = ((const float4*)bu)[(f4 + i) & 31];
    }

    // ---- inline staging: fp32 -> bf16 -> swizzled LDS image ----
    const float* wsel = (which == 0) ? Wq : (which == 1) ? Wk : Wv;
    const float* Asrc = x + (size_t)(bx * 128) * 128;
    const float* Bsrc = wsel + (size_t)(h_ * 128) * 128;

    {
        int row = tid >> 1, half = tid & 1;
        const float* ar = Asrc + (size_t)row * 128 + half * 64;
        const float* br = Bsrc + (size_t)row * 128 + half * 64;
#pragma unroll
        for (int c2 = 0; c2 < 8; c2++) {
            int c = half * 8 + c2;
            int dst = row * 128 + ((c ^ (row & 15)) << 3);
            float4 fa0 = *(const float4*)(ar + c2 * 8);
            float4 fa1 = *(const float4*)(ar + c2 * 8 + 4);
            unsigned short oa[8];
            oa[0] = f2bf(fa0.x); oa[1] = f2bf(fa0.y); oa[2] = f2bf(fa0.z); oa[3] = f2bf(fa0.w);
            oa[4] = f2bf(fa1.x); oa[5] = f2bf(fa1.y); oa[6] = f2bf(fa1.z); oa[7] = f2bf(fa1.w);
            *(ushort4*)(&As[dst])     = *(ushort4*)&oa[0];
            *(ushort4*)(&As[dst + 4]) = *(ushort4*)&oa[4];
            float4 fb0 = *(const float4*)(br + c2 * 8);
            float4 fb1 = *(const float4*)(br + c2 * 8 + 4);
            unsigned short ob[8];
            ob[0] = f2bf(fb0.x); ob[1] = f2bf(fb0.y); ob[2] = f2bf(fb0.z); ob[3] = f2bf(fb0.w);
            ob[4] = f2bf(fb1.x); ob[5] = f2bf(fb1.y); ob[6] = f2bf(fb1.z); ob[7] = f2bf(fb1.w);
            *(ushort4*)(&Bs[dst])     = *(ushort4*)&ob[0];
            *(ushort4*)(&Bs[dst + 4]) = *(ushort4*)&ob[4];
        }
    }
    __syncthreads();

    // ---- MFMA body (R12, unchanged) ----
    bf16x8 a[4][4];
#pragma unroll
    for (int mt = 0; mt < 4; mt++) {
        int row = wm * 64 + mt * 16 + l16;
#pragma unroll
        for (int ks = 0; ks < 4; ks++)
            a[mt][ks] = *(const bf16x8*)(&As[row * 128 + (((ks * 4 + quad) ^ (row & 15)) << 3)]);
    }

    f32x4 acc[4][4];
#pragma unroll
    for (int nt = 0; nt < 4; nt++) {
        int row = wn * 64 + nt * 16 + l16;
        bf16x8 b4[4];
#pragma unroll
        for (int ks = 0; ks < 4; ks++)
            b4[ks] = *(const bf16x8*)(&Bs[row * 128 + (((ks * 4 + quad) ^ (row & 15)) << 3)]);
#pragma unroll
        for (int mt = 0; mt < 4; mt++) {
            f32x4 c = {0.f, 0.f, 0.f, 0.f};
#pragma unroll
            for (int ks = 0; ks < 4; ks++)
                c = __builtin_amdgcn_mfma_f32_16x16x32_bf16(a[mt][ks], b4[ks], c, 0, 0, 0);
            acc[mt][nt] = c;
        }
    }

    const int b_ = bx >> 3;
    if (which < 2) {
        // fp8 convert -> LDS tile (128x144B) -> coalesced global stores
        __syncthreads();
        char* escr = (char*)As;
#pragma unroll
        for (int mt = 0; mt < 4; mt++) {
#pragma unroll
            for (int nt = 0; nt < 4; nt++) {
                int w = __builtin_amdgcn_cvt_pk_fp8_f32(acc[mt][nt][0], acc[mt][nt][1], 0, false);
                w = __builtin_amdgcn_cvt_pk_fp8_f32(acc[mt][nt][2], acc[mt][nt][3], w, true);
                int col = wn * 64 + nt * 16 + l16;
#pragma unroll
                for (int r = 0; r < 4; r++)
                    escr[(wm * 64 + mt * 16 + quad * 4 + r) * 144 + col] = (char)(w >> (8 * r));
            }
        }
        __syncthreads();
        int row = tid >> 1;
        int t_in = (bx & 7) * 128 + row;
        char* dst = (which == 0) ? Q : K;
        size_t rowbase = ((size_t)((b_ * Hn + h_) * Tn + t_in)) * 128;
#pragma unroll
        for (int i = 0; i < 4; i++) {
            int c = (tid & 1) * 4 + i;
            int4 v = *(const int4*)(escr + row * 144 + c * 16);
            int cc = (which == 1) ? (c ^ (row & 7)) : c;
            *(int4*)(dst + rowbase + cc * 16) = v;
        }
    } else {
        // V bf16 direct tiled stores
#pragma unroll
        for (int mt = 0; mt < 4; mt++) {
            int m_base = bx * 128 + wm * 64 + mt * 16 + quad * 4;
            int t0 = m_base & 1023;
#pragma unroll
            for (int nt = 0; nt < 4; nt++) {
                int e_ = wn * 64 + nt * 16 + l16;
                int kt_ = t0 >> 6, tc0 = t0 & 63;
                size_t off = ((((size_t)(b_ * Hn + h_) * 16 + kt_) * 128 + e_) << 6)
                           + ((((tc0 >> 3) ^ (e_ & 7)) << 3) | (tc0 & 7));
                ushort4 v4;
                v4.x = f2bf(acc[mt][nt][0]); v4.y = f2bf(acc[mt][nt][1]);
                v4.z = f2bf(acc[mt][nt][2]); v4.w = f2bf(acc[mt][nt][3]);
                *(ushort4*)(Vt + off) = v4;
            }
        }
    }
}

// ---------------- dispatch 2: flash attention (R14, unchanged) + fused outproj ----------------
__global__ __launch_bounds__(256, 2) void attn_kernel(
    const char* __restrict__ Q,               // fp8 [64][1024][128] plain
    const char* __restrict__ K,               // fp8 [64][1024][128] chunk swizzle c^(t&7)
    const unsigned short* __restrict__ Vt,    // bf16 [64][16][128][64] tiled+swizzled
    const unsigned long long* __restrict__ mbits, // [16][1024] transposed
    const unsigned short* __restrict__ wuF,   // [((h*4+ks)*8+nt)*64+lane][8]
    float* __restrict__ out)                  // [8192][128] fp32, bias-preset
{
    const int id   = blockIdx.x;
    const int qb   = (id & 7) ^ (7 * ((id >> 8) & 1));
    const int bh   = (id >> 3) & 63;
    const int wave = threadIdx.x >> 6;
    const int lane = threadIdx.x & 63;
    const int l16  = lane & 15;
    const int quad = lane >> 4;

    __shared__ __align__(16) char kbuf[2][64 * 128];            // 8 KB each
    __shared__ __align__(16) unsigned short vbuf[2][128 * 64];  // 16 KB each

    const char* Qb = Q  + (size_t)bh * Tn * Dn;
    const char* Kb = K  + (size_t)bh * Tn * Dn;
    const unsigned short* Vb = Vt + (size_t)bh * (16 * 128 * 64);

    const int blkkt = 2 * qb + 1;
    const int q0w   = qb * 128 + wave * 32;
    const int q0s[2] = { q0w, q0w + 16 };
    const int wkmax = (q0w + 31) >> 6;

    long qf[2][4];
#pragma unroll
    for (int st = 0; st < 2; st++)
#pragma unroll
        for (int ks = 0; ks < 4; ks++)
            qf[st][ks] = *(const long*)(Qb + (size_t)(q0s[st] + l16) * 128 + ks * 32 + quad * 8);

    bf16x8 ones;
#pragma unroll
    for (int j = 0; j < 8; j++) ones[j] = (short)0x3F80;

    f32x4 o[2][8];
#pragma unroll
    for (int st = 0; st < 2; st++)
#pragma unroll
        for (int et = 0; et < 8; et++) o[st][et] = (f32x4){0.f, 0.f, 0.f, 0.f};
    f32x4 lacc[2];
    lacc[0] = (f32x4){0.f, 0.f, 0.f, 0.f};
    lacc[1] = (f32x4){0.f, 0.f, 0.f, 0.f};

    const float SL = 0.12752041570284543f;  // 1/sqrt(128) * log2(e)

    const int idx0 = (l16 << 2) + ((quad & 1) << 7);
    const int idx1 = idx0 + 64;
    const bool hiQ = (quad >> 1) != 0;

#pragma unroll
    for (int i = 0; i < 2; i++) {
        int base = (wave * 2 + i) * 1024;
        gload_lds16b(Kb + base + lane * 16, &kbuf[0][base]);
    }
#pragma unroll
    for (int i = 0; i < 4; i++) {
        int base = (wave * 4 + i) * 512;
        gload_lds16(Vb + base + lane * 8, &vbuf[0][base]);
    }

    for (int kt = 0; kt <= blkkt; kt++) {
        const int cur = kt & 1;
        __syncthreads();

        if (kt < blkkt) {
            const char* Kg = Kb + (kt + 1) * (64 * 128);
            const unsigned short* Vg = Vb + (kt + 1) * (128 * 64);
#pragma unroll
            for (int i = 0; i < 2; i++) {
                int base = (wave * 2 + i) * 1024;
                gload_lds16b(Kg + base + lane * 16, &kbuf[cur ^ 1][base]);
            }
#pragma unroll
            for (int i = 0; i < 4; i++) {
                int base = (wave * 4 + i) * 512;
                gload_lds16(Vg + base + lane * 8, &vbuf[cur ^ 1][base]);
            }
        }

        if (kt <= wkmax) {
            unsigned long long mw[2];
            mw[0] = mbits[kt * Tn + q0s[0] + l16];
            mw[1] = mbits[kt * Tn + q0s[1] + l16];

            f32x4 s[2][4];
#pragma unroll
            for (int nt = 0; nt < 4; nt++) {
                int row = nt * 16 + l16;
                long a4[4];
#pragma unroll
                for (int ks = 0; ks < 4; ks++) {
                    int c = ks * 2 + (quad >> 1);
                    a4[ks] = *(const long*)(&kbuf[cur][row * 128 + (((c ^ (row & 7)) << 4) | ((quad & 1) << 3))]);
                }
#pragma unroll
                for (int st = 0; st < 2; st++) {
                    f32x4 c = {0.f, 0.f, 0.f, 0.f};
#pragma unroll
                    for (int ks = 0; ks < 4; ks++)
                        c = __builtin_amdgcn_mfma_f32_16x16x32_fp8_fp8(a4[ks], qf[st][ks], c, 0, 0, 0);
                    s[st][nt] = c;
                }
            }

            const int kc0 = kt * 64;
            bf16x8 pf[2][2];
#pragma unroll
            for (int st = 0; st < 2; st++) {
                const int qglob = q0s[st] + l16;
                int w[4][2];
#pragma unroll
                for (int nt = 0; nt < 4; nt++) {
                    float pv[4];
#pragma unroll
                    for (int r = 0; r < 4; r++) {
                        int bit = nt * 16 + quad * 4 + r;
                        bool live = ((mw[st] >> bit) & 1ULL) && (kc0 + bit <= qglob);
                        pv[r] = live ? __builtin_amdgcn_exp2f(s[st][nt][r] * SL) : 0.f;
                    }
                    w[nt][0] = pack_bf16_trunc(pv[0], pv[1]);
                    w[nt][1] = pack_bf16_trunc(pv[2], pv[3]);
                }
#pragma unroll
                for (int k2 = 0; k2 < 2; k2++) {
                    union { int i[4]; bf16x8 v; } u;
#pragma unroll
                    for (int d = 0; d < 4; d++) {
                        int idx = (d < 2) ? idx0 : idx1;
                        int va = __builtin_amdgcn_ds_bpermute(idx, w[2 * k2][d & 1]);
                        int vb = __builtin_amdgcn_ds_bpermute(idx, w[2 * k2 + 1][d & 1]);
                        u.i[d] = hiQ ? vb : va;
                    }
                    pf[st][k2] = u.v;
                }
            }

#pragma unroll
            for (int st = 0; st < 2; st++)
#pragma unroll
                for (int k2 = 0; k2 < 2; k2++)
                    lacc[st] = __builtin_amdgcn_mfma_f32_16x16x32_bf16(pf[st][k2], ones, lacc[st], 0, 0, 0);

#pragma unroll
            for (int et = 0; et < 8; et++) {
                int row = et * 16 + l16;
#pragma unroll
                for (int k2 = 0; k2 < 2; k2++) {
                    bf16x8 b = *(const bf16x8*)(&vbuf[cur][row * 64 + (((k2 * 4 + quad) ^ (l16 & 7)) << 3)]);
                    o[0][et] = __builtin_amdgcn_mfma_f32_16x16x32_bf16(pf[0][k2], b, o[0][et], 0, 0, 0);
                    o[1][et] = __builtin_amdgcn_mfma_f32_16x16x32_bf16(pf[1][k2], b, o[1][et], 0, 0, 0);
                }
            }
        }
    }

    // phase 2: degenerate rows (l == 0) attend uniformly over all mask==0 keys
    __syncthreads();
    {
        bool deg = false;
#pragma unroll
        for (int st = 0; st < 2; st++)
#pragma unroll
            for (int r = 0; r < 4; r++) deg |= (lacc[st][r] == 0.f);
        if (__ballot(deg) != 0ULL) {
            unsigned short* pb = (unsigned short*)((char*)kbuf + wave * 2304);  // 16 x 72 shorts
            unsigned short dsel[2][4];
#pragma unroll
            for (int st = 0; st < 2; st++)
#pragma unroll
                for (int r = 0; r < 4; r++)
                    dsel[st][r] = (lacc[st][r] == 0.f) ? (unsigned short)0x3F80 : (unsigned short)0;
            for (int kt = 0; kt < 16; kt++) {
#pragma unroll
                for (int st = 0; st < 2; st++) {
                    int qrow = q0s[st] + quad * 4;
                    unsigned long long mw2[4];
#pragma unroll
                    for (int r = 0; r < 4; r++) mw2[r] = mbits[kt * Tn + qrow + r];
#pragma unroll
                    for (int nt = 0; nt < 4; nt++) {
                        int bi = nt * 16 + l16;
#pragma unroll
                        for (int r = 0; r < 4; r++)
                            pb[(quad * 4 + r) * 72 + bi] = ((mw2[r] >> bi) & 1ULL) ? (unsigned short)0 : dsel[st][r];
                    }
                    bf16x8 pf[2];
#pragma unroll
                    for (int k2 = 0; k2 < 2; k2++)
                        pf[k2] = *(const bf16x8*)(&pb[l16 * 72 + k2 * 32 + quad * 8]);
#pragma unroll
                    for (int k2 = 0; k2 < 2; k2++)
                        lacc[st] = __builtin_amdgcn_mfma_f32_16x16x32_bf16(pf[k2], ones, lacc[st], 0, 0, 0);
                    const unsigned short* Vg = Vb + kt * (128 * 64);
#pragma unroll
                    for (int et = 0; et < 8; et++) {
#pragma unroll
                        for (int k2 = 0; k2 < 2; k2++) {
                            bf16x8 b = *(const bf16x8*)(Vg + (et * 16 + l16) * 64 + (((k2 * 4 + quad) ^ (l16 & 7)) << 3));
                            o[st][et] = __builtin_amdgcn_mfma_f32_16x16x32_bf16(pf[k2], b, o[st][et], 0, 0, 0);
                        }
                    }
                }
            }
        }
    }

    // fused output projection epilogue
    const int b_ = bh >> 3, h_ = bh & 7;
    const unsigned short* wf = wuF + (size_t)h_ * (4 * 8 * 64 * 8);
#pragma unroll
    for (int st = 0; st < 2; st++) {
        unsigned short* tile = (unsigned short*)((char*)vbuf + wave * 4608);  // 16 x 144 shorts
#pragma unroll
        for (int r = 0; r < 4; r++) {
            float inv = 1.f / lacc[st][r];
            int row = quad * 4 + r;
#pragma unroll
            for (int et = 0; et < 8; et++)
                tile[row * 144 + et * 16 + l16] = f2bf(o[st][et][r] * inv);
        }

        bf16x8 a4[4];
#pragma unroll
        for (int ks = 0; ks < 4; ks++)
            a4[ks] = *(const bf16x8*)(&tile[l16 * 144 + ks * 32 + quad * 8]);

        f32x4 acc2[8];
#pragma unroll
        for (int nt = 0; nt < 8; nt++) acc2[nt] = (f32x4){0.f, 0.f, 0.f, 0.f};
#pragma unroll
        for (int ks = 0; ks < 4; ks++) {
#pragma unroll
            for (int nt = 0; nt < 8; nt++) {
                bf16x8 b = *(const bf16x8*)(wf + ((size_t)(ks * 8 + nt) * 64 + lane) * 8);
                acc2[nt] = __builtin_amdgcn_mfma_f32_16x16x32_bf16(a4[ks], b, acc2[nt], 0, 0, 0);
            }
        }

#pragma unroll
        for (int nt = 0; nt < 8; nt++) {
            int n = nt * 16 + l16;
#pragma unroll
            for (int r = 0; r < 4; r++) {
                int q = q0s[st] + quad * 4 + r;
                atomicAdd(&out[(size_t)(b_ * Tn + q) * Dn + n], acc2[nt][r]);
            }
        }
    }
}

extern "C" void kernel_launch(void* const* d_in, const int* in_sizes, int n_in,
                              void* d_out, int out_size, void* d_ws, size_t ws_size,
                              hipStream_t stream) {
    const float* x   = (const float*)d_in[0];
    const int* mask  = (const int*)d_in[1];
    const float* Wk  = (const float*)d_in[2];
    const float* Wq  = (const float*)d_in[3];
    const float* Wv  = (const float*)d_in[4];
    const float* Wu  = (const float*)d_in[5];
    const float* bu  = (const float*)d_in[6];
    float* out = (float*)d_out;

    char* ws = (char*)d_ws;
    unsigned short* wuF = (unsigned short*)ws; ws += (size_t)128 * 1024 * 2;
    char* Qf  = ws; ws += (size_t)64 * 1024 * 128;
    char* Kf  = ws; ws += (size_t)64 * 1024 * 128;
    unsigned short* Vtw = (unsigned short*)ws; ws += (size_t)64 * 1024 * 128 * 2;
    unsigned long long* mb = (unsigned long long*)ws; ws += (size_t)1024 * 16 * 8;

    qkv_kernel<<<dim3(64, 24), 256, 0, stream>>>(x, Wq, Wk, Wv, Wu, mask, bu, out,
                                                 wuF, mb, Qf, Kf, Vtw);
    attn_kernel<<<dim3(512), 256, 0, stream>>>(Qf, Kf, Vtw, mb, wuF, out);
}

// Round 19
// 147.114 us; speedup vs baseline: 3.3813x; 1.0754x over previous
//
#include <hip/hip_runtime.h>

#define Bn 8
#define Hn 8
#define Tn 1024
#define Dn 128

typedef __attribute__((ext_vector_type(8))) short bf16x8;
typedef __attribute__((ext_vector_type(4))) float f32x4;

typedef __attribute__((address_space(3))) unsigned int lds_as_t;
typedef __attribute__((address_space(1))) const unsigned int glb_as_t;

static __device__ __forceinline__ void gload_lds16(const unsigned short* g, unsigned short* l) {
    __builtin_amdgcn_global_load_lds((glb_as_t*)g, (lds_as_t*)l, 16, 0, 0);
}
static __device__ __forceinline__ void gload_lds16b(const char* g, char* l) {
    __builtin_amdgcn_global_load_lds((glb_as_t*)g, (lds_as_t*)l, 16, 0, 0);
}

static __device__ __forceinline__ unsigned short f2bf(float f) {
    union { float f; unsigned int u; } v; v.f = f;
    unsigned int u = v.u;
    return (unsigned short)((u + 0x7FFFu + ((u >> 16) & 1u)) >> 16);
}
static __device__ __forceinline__ int pack_bf16_trunc(float lo, float hi) {
    union { float f; unsigned int u; } a, b;
    a.f = lo; b.f = hi;
    return (int)__builtin_amdgcn_perm(b.u, a.u, 0x07060302u);
}

// ---------------- dispatch 1: fused prep + QKV GEMM ----------------
// grid (64, 24): which = by>>3 in {Q,K,V}; head = by&7; m-tile = bx.
// COALESCED inline staging: flat float4 loads (1024 consecutive floats per wave
// instruction), RNE convert in registers, swizzled LDS image write.
// Side work: which==0 -> mask bitpack; which==1 -> wuF reorder; which==2 -> out=bias.
__global__ __launch_bounds__(256, 2) void qkv_kernel(
    const float* __restrict__ x,  const float* __restrict__ Wq,
    const float* __restrict__ Wk, const float* __restrict__ Wv,
    const float* __restrict__ Wu, const int* __restrict__ mask,
    const float* __restrict__ bu, float* __restrict__ out,
    unsigned short* __restrict__ wuF, unsigned long long* __restrict__ mbits,
    char* __restrict__ Q, char* __restrict__ K, unsigned short* __restrict__ Vt)
{
    const int bx = blockIdx.x, by = blockIdx.y;
    const int tid  = threadIdx.x;
    const int wave = tid >> 6;
    const int lane = tid & 63;
    const int l16  = lane & 15;
    const int quad = lane >> 4;
    const int wm = wave & 1, wn = wave >> 1;
    const int which = by >> 3;
    const int h_ = by & 7;
    const int bid = h_ * 64 + bx;          // 0..511 within this 'which' group

    __shared__ __align__(16) unsigned short As[128 * 128];
    __shared__ __align__(16) unsigned short Bs[128 * 128];

    // ---- side work (independent of the GEMM; consumed by dispatch 2) ----
    if (which == 0) {
        int base = (bid * 4 + wave) * 8;
#pragma unroll
        for (int i = 0; i < 8; i++) {
            int widx = base + i;
            int row = widx >> 4, kt = widx & 15;
            int v = mask[row * Tn + kt * 64 + lane];
            unsigned long long b = __ballot(v != 0);
            if (lane == 0) mbits[kt * Tn + row] = b;
        }
    } else if (which == 1) {
        if (tid < 32) {
            int id = bid * 32 + tid;
            int lane_ = id & 63;
            int fid = id >> 6;               // ((h*4+ks)*8+nt)
            int nt = fid & 7, ks = (fid >> 3) & 3, h = fid >> 5;
            int row = nt * 16 + (lane_ & 15);
            int col = h * 128 + ks * 32 + (lane_ >> 4) * 8;
            const float* src = Wu + (size_t)row * 1024 + col;
            float4 f0 = *(const float4*)(src);
            float4 f1 = *(const float4*)(src + 4);
            unsigned short o[8];
            o[0] = f2bf(f0.x); o[1] = f2bf(f0.y); o[2] = f2bf(f0.z); o[3] = f2bf(f0.w);
            o[4] = f2bf(f1.x); o[5] = f2bf(f1.y); o[6] = f2bf(f1.z); o[7] = f2bf(f1.w);
            *(ushort4*)(wuF + (size_t)id * 8)     = *(ushort4*)&o[0];
            *(ushort4*)(wuF + (size_t)id * 8 + 4) = *(ushort4*)&o[4];
        }
    } else {
        int f4 = bid * 512 + tid * 2;
#pragma unroll
        for (int i = 0; i < 2; i++)
            ((float4*)out)[f4 + i] = ((const float4*)bu)[(f4 + i) & 31];
    }

    // ---- COALESCED staging: fp32 -> bf16 -> swizzled LDS image ----
    const float* wsel = (which == 0) ? Wq : (which == 1) ? Wk : Wv;
    const float* Asrc = x + (size_t)(bx * 128) * 128;
    const float* Bsrc = wsel + (size_t)(h_ * 128) * 128;

#pragma unroll
    for (int it = 0; it < 16; it++) {
        int idx = it * 1024 + tid * 4;       // flat fp32 index in 128x128 tile
        int row = idx >> 7, col = idx & 127;
        int dst = row * 128 + ((((col >> 3) ^ (row & 15)) << 3) | (col & 7));
        float4 fa = *(const float4*)(Asrc + idx);
        ushort4 oa;
        oa.x = f2bf(fa.x); oa.y = f2bf(fa.y); oa.z = f2bf(fa.z); oa.w = f2bf(fa.w);
        *(ushort4*)(&As[dst]) = oa;
        float4 fb = *(const float4*)(Bsrc + idx);
        ushort4 ob;
        ob.x = f2bf(fb.x); ob.y = f2bf(fb.y); ob.z = f2bf(fb.z); ob.w = f2bf(fb.w);
        *(ushort4*)(&Bs[dst]) = ob;
    }
    __syncthreads();

    // ---- MFMA body (R12, unchanged) ----
    bf16x8 a[4][4];
#pragma unroll
    for (int mt = 0; mt < 4; mt++) {
        int row = wm * 64 + mt * 16 + l16;
#pragma unroll
        for (int ks = 0; ks < 4; ks++)
            a[mt][ks] = *(const bf16x8*)(&As[row * 128 + (((ks * 4 + quad) ^ (row & 15)) << 3)]);
    }

    f32x4 acc[4][4];
#pragma unroll
    for (int nt = 0; nt < 4; nt++) {
        int row = wn * 64 + nt * 16 + l16;
        bf16x8 b4[4];
#pragma unroll
        for (int ks = 0; ks < 4; ks++)
            b4[ks] = *(const bf16x8*)(&Bs[row * 128 + (((ks * 4 + quad) ^ (row & 15)) << 3)]);
#pragma unroll
        for (int mt = 0; mt < 4; mt++) {
            f32x4 c = {0.f, 0.f, 0.f, 0.f};
#pragma unroll
            for (int ks = 0; ks < 4; ks++)
                c = __builtin_amdgcn_mfma_f32_16x16x32_bf16(a[mt][ks], b4[ks], c, 0, 0, 0);
            acc[mt][nt] = c;
        }
    }

    const int b_ = bx >> 3;
    if (which < 2) {
        __syncthreads();
        char* escr = (char*)As;
#pragma unroll
        for (int mt = 0; mt < 4; mt++) {
#pragma unroll
            for (int nt = 0; nt < 4; nt++) {
                int w = __builtin_amdgcn_cvt_pk_fp8_f32(acc[mt][nt][0], acc[mt][nt][1], 0, false);
                w = __builtin_amdgcn_cvt_pk_fp8_f32(acc[mt][nt][2], acc[mt][nt][3], w, true);
                int col = wn * 64 + nt * 16 + l16;
#pragma unroll
                for (int r = 0; r < 4; r++)
                    escr[(wm * 64 + mt * 16 + quad * 4 + r) * 144 + col] = (char)(w >> (8 * r));
            }
        }
        __syncthreads();
        int row = tid >> 1;
        int t_in = (bx & 7) * 128 + row;
        char* dst = (which == 0) ? Q : K;
        size_t rowbase = ((size_t)((b_ * Hn + h_) * Tn + t_in)) * 128;
#pragma unroll
        for (int i = 0; i < 4; i++) {
            int c = (tid & 1) * 4 + i;
            int4 v = *(const int4*)(escr + row * 144 + c * 16);
            int cc = (which == 1) ? (c ^ (row & 7)) : c;
            *(int4*)(dst + rowbase + cc * 16) = v;
        }
    } else {
#pragma unroll
        for (int mt = 0; mt < 4; mt++) {
            int m_base = bx * 128 + wm * 64 + mt * 16 + quad * 4;
            int t0 = m_base & 1023;
#pragma unroll
            for (int nt = 0; nt < 4; nt++) {
                int e_ = wn * 64 + nt * 16 + l16;
                int kt_ = t0 >> 6, tc0 = t0 & 63;
                size_t off = ((((size_t)(b_ * Hn + h_) * 16 + kt_) * 128 + e_) << 6)
                           + ((((tc0 >> 3) ^ (e_ & 7)) << 3) | (tc0 & 7));
                ushort4 v4;
                v4.x = f2bf(acc[mt][nt][0]); v4.y = f2bf(acc[mt][nt][1]);
                v4.z = f2bf(acc[mt][nt][2]); v4.w = f2bf(acc[mt][nt][3]);
                *(ushort4*)(Vt + off) = v4;
            }
        }
    }
}

// ---------------- dispatch 2: flash attention (R14, unchanged) + fused outproj ----------------
__global__ __launch_bounds__(256, 2) void attn_kernel(
    const char* __restrict__ Q,               // fp8 [64][1024][128] plain
    const char* __restrict__ K,               // fp8 [64][1024][128] chunk swizzle c^(t&7)
    const unsigned short* __restrict__ Vt,    // bf16 [64][16][128][64] tiled+swizzled
    const unsigned long long* __restrict__ mbits, // [16][1024] transposed
    const unsigned short* __restrict__ wuF,   // [((h*4+ks)*8+nt)*64+lane][8]
    float* __restrict__ out)                  // [8192][128] fp32, bias-preset
{
    const int id   = blockIdx.x;
    const int qb   = (id & 7) ^ (7 * ((id >> 8) & 1));
    const int bh   = (id >> 3) & 63;
    const int wave = threadIdx.x >> 6;
    const int lane = threadIdx.x & 63;
    const int l16  = lane & 15;
    const int quad = lane >> 4;

    __shared__ __align__(16) char kbuf[2][64 * 128];            // 8 KB each
    __shared__ __align__(16) unsigned short vbuf[2][128 * 64];  // 16 KB each

    const char* Qb = Q  + (size_t)bh * Tn * Dn;
    const char* Kb = K  + (size_t)bh * Tn * Dn;
    const unsigned short* Vb = Vt + (size_t)bh * (16 * 128 * 64);

    const int blkkt = 2 * qb + 1;
    const int q0w   = qb * 128 + wave * 32;
    const int q0s[2] = { q0w, q0w + 16 };
    const int wkmax = (q0w + 31) >> 6;

    long qf[2][4];
#pragma unroll
    for (int st = 0; st < 2; st++)
#pragma unroll
        for (int ks = 0; ks < 4; ks++)
            qf[st][ks] = *(const long*)(Qb + (size_t)(q0s[st] + l16) * 128 + ks * 32 + quad * 8);

    bf16x8 ones;
#pragma unroll
    for (int j = 0; j < 8; j++) ones[j] = (short)0x3F80;

    f32x4 o[2][8];
#pragma unroll
    for (int st = 0; st < 2; st++)
#pragma unroll
        for (int et = 0; et < 8; et++) o[st][et] = (f32x4){0.f, 0.f, 0.f, 0.f};
    f32x4 lacc[2];
    lacc[0] = (f32x4){0.f, 0.f, 0.f, 0.f};
    lacc[1] = (f32x4){0.f, 0.f, 0.f, 0.f};

    const float SL = 0.12752041570284543f;  // 1/sqrt(128) * log2(e)

    const int idx0 = (l16 << 2) + ((quad & 1) << 7);
    const int idx1 = idx0 + 64;
    const bool hiQ = (quad >> 1) != 0;

#pragma unroll
    for (int i = 0; i < 2; i++) {
        int base = (wave * 2 + i) * 1024;
        gload_lds16b(Kb + base + lane * 16, &kbuf[0][base]);
    }
#pragma unroll
    for (int i = 0; i < 4; i++) {
        int base = (wave * 4 + i) * 512;
        gload_lds16(Vb + base + lane * 8, &vbuf[0][base]);
    }

    for (int kt = 0; kt <= blkkt; kt++) {
        const int cur = kt & 1;
        __syncthreads();

        if (kt < blkkt) {
            const char* Kg = Kb + (kt + 1) * (64 * 128);
            const unsigned short* Vg = Vb + (kt + 1) * (128 * 64);
#pragma unroll
            for (int i = 0; i < 2; i++) {
                int base = (wave * 2 + i) * 1024;
                gload_lds16b(Kg + base + lane * 16, &kbuf[cur ^ 1][base]);
            }
#pragma unroll
            for (int i = 0; i < 4; i++) {
                int base = (wave * 4 + i) * 512;
                gload_lds16(Vg + base + lane * 8, &vbuf[cur ^ 1][base]);
            }
        }

        if (kt <= wkmax) {
            unsigned long long mw[2];
            mw[0] = mbits[kt * Tn + q0s[0] + l16];
            mw[1] = mbits[kt * Tn + q0s[1] + l16];

            f32x4 s[2][4];
#pragma unroll
            for (int nt = 0; nt < 4; nt++) {
                int row = nt * 16 + l16;
                long a4[4];
#pragma unroll
                for (int ks = 0; ks < 4; ks++) {
                    int c = ks * 2 + (quad >> 1);
                    a4[ks] = *(const long*)(&kbuf[cur][row * 128 + (((c ^ (row & 7)) << 4) | ((quad & 1) << 3))]);
                }
#pragma unroll
                for (int st = 0; st < 2; st++) {
                    f32x4 c = {0.f, 0.f, 0.f, 0.f};
#pragma unroll
                    for (int ks = 0; ks < 4; ks++)
                        c = __builtin_amdgcn_mfma_f32_16x16x32_fp8_fp8(a4[ks], qf[st][ks], c, 0, 0, 0);
                    s[st][nt] = c;
                }
            }

            const int kc0 = kt * 64;
            bf16x8 pf[2][2];
#pragma unroll
            for (int st = 0; st < 2; st++) {
                const int qglob = q0s[st] + l16;
                int w[4][2];
#pragma unroll
                for (int nt = 0; nt < 4; nt++) {
                    float pv[4];
#pragma unroll
                    for (int r = 0; r < 4; r++) {
                        int bit = nt * 16 + quad * 4 + r;
                        bool live = ((mw[st] >> bit) & 1ULL) && (kc0 + bit <= qglob);
                        pv[r] = live ? __builtin_amdgcn_exp2f(s[st][nt][r] * SL) : 0.f;
                    }
                    w[nt][0] = pack_bf16_trunc(pv[0], pv[1]);
                    w[nt][1] = pack_bf16_trunc(pv[2], pv[3]);
                }
#pragma unroll
                for (int k2 = 0; k2 < 2; k2++) {
                    union { int i[4]; bf16x8 v; } u;
#pragma unroll
                    for (int d = 0; d < 4; d++) {
                        int idx = (d < 2) ? idx0 : idx1;
                        int va = __builtin_amdgcn_ds_bpermute(idx, w[2 * k2][d & 1]);
                        int vb = __builtin_amdgcn_ds_bpermute(idx, w[2 * k2 + 1][d & 1]);
                        u.i[d] = hiQ ? vb : va;
                    }
                    pf[st][k2] = u.v;
                }
            }

#pragma unroll
            for (int st = 0; st < 2; st++)
#pragma unroll
                for (int k2 = 0; k2 < 2; k2++)
                    lacc[st] = __builtin_amdgcn_mfma_f32_16x16x32_bf16(pf[st][k2], ones, lacc[st], 0, 0, 0);

#pragma unroll
            for (int et = 0; et < 8; et++) {
                int row = et * 16 + l16;
#pragma unroll
                for (int k2 = 0; k2 < 2; k2++) {
                    bf16x8 b = *(const bf16x8*)(&vbuf[cur][row * 64 + (((k2 * 4 + quad) ^ (l16 & 7)) << 3)]);
                    o[0][et] = __builtin_amdgcn_mfma_f32_16x16x32_bf16(pf[0][k2], b, o[0][et], 0, 0, 0);
                    o[1][et] = __builtin_amdgcn_mfma_f32_16x16x32_bf16(pf[1][k2], b, o[1][et], 0, 0, 0);
                }
            }
        }
    }

    // phase 2: degenerate rows (l == 0) attend uniformly over all mask==0 keys
    __syncthreads();
    {
        bool deg = false;
#pragma unroll
        for (int st = 0; st < 2; st++)
#pragma unroll
            for (int r = 0; r < 4; r++) deg |= (lacc[st][r] == 0.f);
        if (__ballot(deg) != 0ULL) {
            unsigned short* pb = (unsigned short*)((char*)kbuf + wave * 2304);  // 16 x 72 shorts
            unsigned short dsel[2][4];
#pragma unroll
            for (int st = 0; st < 2; st++)
#pragma unroll
                for (int r = 0; r < 4; r++)
                    dsel[st][r] = (lacc[st][r] == 0.f) ? (unsigned short)0x3F80 : (unsigned short)0;
            for (int kt = 0; kt < 16; kt++) {
#pragma unroll
                for (int st = 0; st < 2; st++) {
                    int qrow = q0s[st] + quad * 4;
                    unsigned long long mw2[4];
#pragma unroll
                    for (int r = 0; r < 4; r++) mw2[r] = mbits[kt * Tn + qrow + r];
#pragma unroll
                    for (int nt = 0; nt < 4; nt++) {
                        int bi = nt * 16 + l16;
#pragma unroll
                        for (int r = 0; r < 4; r++)
                            pb[(quad * 4 + r) * 72 + bi] = ((mw2[r] >> bi) & 1ULL) ? (unsigned short)0 : dsel[st][r];
                    }
                    bf16x8 pf[2];
#pragma unroll
                    for (int k2 = 0; k2 < 2; k2++)
                        pf[k2] = *(const bf16x8*)(&pb[l16 * 72 + k2 * 32 + quad * 8]);
#pragma unroll
                    for (int k2 = 0; k2 < 2; k2++)
                        lacc[st] = __builtin_amdgcn_mfma_f32_16x16x32_bf16(pf[k2], ones, lacc[st], 0, 0, 0);
                    const unsigned short* Vg = Vb + kt * (128 * 64);
#pragma unroll
                    for (int et = 0; et < 8; et++) {
#pragma unroll
                        for (int k2 = 0; k2 < 2; k2++) {
                            bf16x8 b = *(const bf16x8*)(Vg + (et * 16 + l16) * 64 + (((k2 * 4 + quad) ^ (l16 & 7)) << 3));
                            o[st][et] = __builtin_amdgcn_mfma_f32_16x16x32_bf16(pf[k2], b, o[st][et], 0, 0, 0);
                        }
                    }
                }
            }
        }
    }

    // fused output projection epilogue
    const int b_ = bh >> 3, h_ = bh & 7;
    const unsigned short* wf = wuF + (size_t)h_ * (4 * 8 * 64 * 8);
#pragma unroll
    for (int st = 0; st < 2; st++) {
        unsigned short* tile = (unsigned short*)((char*)vbuf + wave * 4608);  // 16 x 144 shorts
#pragma unroll
        for (int r = 0; r < 4; r++) {
            float inv = 1.f / lacc[st][r];
            int row = quad * 4 + r;
#pragma unroll
            for (int et = 0; et < 8; et++)
                tile[row * 144 + et * 16 + l16] = f2bf(o[st][et][r] * inv);
        }

        bf16x8 a4[4];
#pragma unroll
        for (int ks = 0; ks < 4; ks++)
            a4[ks] = *(const bf16x8*)(&tile[l16 * 144 + ks * 32 + quad * 8]);

        f32x4 acc2[8];
#pragma unroll
        for (int nt = 0; nt < 8; nt++) acc2[nt] = (f32x4){0.f, 0.f, 0.f, 0.f};
#pragma unroll
        for (int ks = 0; ks < 4; ks++) {
#pragma unroll
            for (int nt = 0; nt < 8; nt++) {
                bf16x8 b = *(const bf16x8*)(wf + ((size_t)(ks * 8 + nt) * 64 + lane) * 8);
                acc2[nt] = __builtin_amdgcn_mfma_f32_16x16x32_bf16(a4[ks], b, acc2[nt], 0, 0, 0);
            }
        }

#pragma unroll
        for (int nt = 0; nt < 8; nt++) {
            int n = nt * 16 + l16;
#pragma unroll
            for (int r = 0; r < 4; r++) {
                int q = q0s[st] + quad * 4 + r;
                atomicAdd(&out[(size_t)(b_ * Tn + q) * Dn + n], acc2[nt][r]);
            }
        }
    }
}

extern "C" void kernel_launch(void* const* d_in, const int* in_sizes, int n_in,
                              void* d_out, int out_size, void* d_ws, size_t ws_size,
                              hipStream_t stream) {
    const float* x   = (const float*)d_in[0];
    const int* mask  = (const int*)d_in[1];
    const float* Wk  = (const float*)d_in[2];
    const float* Wq  = (const float*)d_in[3];
    const float* Wv  = (const float*)d_in[4];
    const float* Wu  = (const float*)d_in[5];
    const float* bu  = (const float*)d_in[6];
    float* out = (float*)d_out;

    char* ws = (char*)d_ws;
    unsigned short* wuF = (unsigned short*)ws; ws += (size_t)128 * 1024 * 2;
    char* Qf  = ws; ws += (size_t)64 * 1024 * 128;
    char* Kf  = ws; ws += (size_t)64 * 1024 * 128;
    unsigned short* Vtw = (unsigned short*)ws; ws += (size_t)64 * 1024 * 128 * 2;
    unsigned long long* mb = (unsigned long long*)ws; ws += (size_t)1024 * 16 * 8;

    qkv_kernel<<<dim3(64, 24), 256, 0, stream>>>(x, Wq, Wk, Wv, Wu, mask, bu, out,
                                                 wuF, mb, Qf, Kf, Vtw);
    attn_kernel<<<dim3(512), 256, 0, stream>>>(Qf, Kf, Vtw, mb, wuF, out);
}

// Round 20
// 142.814 us; speedup vs baseline: 3.4832x; 1.0301x over previous
//
#include <hip/hip_runtime.h>

#define Bn 8
#define Hn 8
#define Tn 1024
#define Dn 128

typedef __attribute__((ext_vector_type(8))) short bf16x8;
typedef __attribute__((ext_vector_type(4))) float f32x4;

typedef __attribute__((address_space(3))) unsigned int lds_as_t;
typedef __attribute__((address_space(1))) const unsigned int glb_as_t;

static __device__ __forceinline__ void gload_lds16(const unsigned short* g, unsigned short* l) {
    __builtin_amdgcn_global_load_lds((glb_as_t*)g, (lds_as_t*)l, 16, 0, 0);
}
static __device__ __forceinline__ void gload_lds16b(const char* g, char* l) {
    __builtin_amdgcn_global_load_lds((glb_as_t*)g, (lds_as_t*)l, 16, 0, 0);
}

static __device__ __forceinline__ unsigned short f2bf(float f) {
    union { float f; unsigned int u; } v; v.f = f;
    unsigned int u = v.u;
    return (unsigned short)((u + 0x7FFFu + ((u >> 16) & 1u)) >> 16);
}
static __device__ __forceinline__ int pack_bf16_trunc(float lo, float hi) {
    union { float f; unsigned int u; } a, b;
    a.f = lo; b.f = hi;
    return (int)__builtin_amdgcn_perm(b.u, a.u, 0x07060302u);
}

// ---------------- dispatch 1: fused prep + QKV GEMM (R19, unchanged) ----------------
__global__ __launch_bounds__(256, 2) void qkv_kernel(
    const float* __restrict__ x,  const float* __restrict__ Wq,
    const float* __restrict__ Wk, const float* __restrict__ Wv,
    const float* __restrict__ Wu, const int* __restrict__ mask,
    const float* __restrict__ bu, float* __restrict__ out,
    unsigned short* __restrict__ wuF, unsigned long long* __restrict__ mbits,
    char* __restrict__ Q, char* __restrict__ K, unsigned short* __restrict__ Vt)
{
    const int bx = blockIdx.x, by = blockIdx.y;
    const int tid  = threadIdx.x;
    const int wave = tid >> 6;
    const int lane = tid & 63;
    const int l16  = lane & 15;
    const int quad = lane >> 4;
    const int wm = wave & 1, wn = wave >> 1;
    const int which = by >> 3;
    const int h_ = by & 7;
    const int bid = h_ * 64 + bx;

    __shared__ __align__(16) unsigned short As[128 * 128];
    __shared__ __align__(16) unsigned short Bs[128 * 128];

    // ---- side work ----
    if (which == 0) {
        int base = (bid * 4 + wave) * 8;
#pragma unroll
        for (int i = 0; i < 8; i++) {
            int widx = base + i;
            int row = widx >> 4, kt = widx & 15;
            int v = mask[row * Tn + kt * 64 + lane];
            unsigned long long b = __ballot(v != 0);
            if (lane == 0) mbits[kt * Tn + row] = b;
        }
    } else if (which == 1) {
        if (tid < 32) {
            int id = bid * 32 + tid;
            int lane_ = id & 63;
            int fid = id >> 6;
            int nt = fid & 7, ks = (fid >> 3) & 3, h = fid >> 5;
            int row = nt * 16 + (lane_ & 15);
            int col = h * 128 + ks * 32 + (lane_ >> 4) * 8;
            const float* src = Wu + (size_t)row * 1024 + col;
            float4 f0 = *(const float4*)(src);
            float4 f1 = *(const float4*)(src + 4);
            unsigned short o[8];
            o[0] = f2bf(f0.x); o[1] = f2bf(f0.y); o[2] = f2bf(f0.z); o[3] = f2bf(f0.w);
            o[4] = f2bf(f1.x); o[5] = f2bf(f1.y); o[6] = f2bf(f1.z); o[7] = f2bf(f1.w);
            *(ushort4*)(wuF + (size_t)id * 8)     = *(ushort4*)&o[0];
            *(ushort4*)(wuF + (size_t)id * 8 + 4) = *(ushort4*)&o[4];
        }
    } else {
        int f4 = bid * 512 + tid * 2;
#pragma unroll
        for (int i = 0; i < 2; i++)
            ((float4*)out)[f4 + i] = ((const float4*)bu)[(f4 + i) & 31];
    }

    // ---- coalesced staging: fp32 -> bf16 -> swizzled LDS image ----
    const float* wsel = (which == 0) ? Wq : (which == 1) ? Wk : Wv;
    const float* Asrc = x + (size_t)(bx * 128) * 128;
    const float* Bsrc = wsel + (size_t)(h_ * 128) * 128;

#pragma unroll
    for (int it = 0; it < 16; it++) {
        int idx = it * 1024 + tid * 4;
        int row = idx >> 7, col = idx & 127;
        int dst = row * 128 + ((((col >> 3) ^ (row & 15)) << 3) | (col & 7));
        float4 fa = *(const float4*)(Asrc + idx);
        ushort4 oa;
        oa.x = f2bf(fa.x); oa.y = f2bf(fa.y); oa.z = f2bf(fa.z); oa.w = f2bf(fa.w);
        *(ushort4*)(&As[dst]) = oa;
        float4 fb = *(const float4*)(Bsrc + idx);
        ushort4 ob;
        ob.x = f2bf(fb.x); ob.y = f2bf(fb.y); ob.z = f2bf(fb.z); ob.w = f2bf(fb.w);
        *(ushort4*)(&Bs[dst]) = ob;
    }
    __syncthreads();

    // ---- MFMA body ----
    bf16x8 a[4][4];
#pragma unroll
    for (int mt = 0; mt < 4; mt++) {
        int row = wm * 64 + mt * 16 + l16;
#pragma unroll
        for (int ks = 0; ks < 4; ks++)
            a[mt][ks] = *(const bf16x8*)(&As[row * 128 + (((ks * 4 + quad) ^ (row & 15)) << 3)]);
    }

    f32x4 acc[4][4];
#pragma unroll
    for (int nt = 0; nt < 4; nt++) {
        int row = wn * 64 + nt * 16 + l16;
        bf16x8 b4[4];
#pragma unroll
        for (int ks = 0; ks < 4; ks++)
            b4[ks] = *(const bf16x8*)(&Bs[row * 128 + (((ks * 4 + quad) ^ (row & 15)) << 3)]);
#pragma unroll
        for (int mt = 0; mt < 4; mt++) {
            f32x4 c = {0.f, 0.f, 0.f, 0.f};
#pragma unroll
            for (int ks = 0; ks < 4; ks++)
                c = __builtin_amdgcn_mfma_f32_16x16x32_bf16(a[mt][ks], b4[ks], c, 0, 0, 0);
            acc[mt][nt] = c;
        }
    }

    const int b_ = bx >> 3;
    if (which < 2) {
        __syncthreads();
        char* escr = (char*)As;
#pragma unroll
        for (int mt = 0; mt < 4; mt++) {
#pragma unroll
            for (int nt = 0; nt < 4; nt++) {
                int w = __builtin_amdgcn_cvt_pk_fp8_f32(acc[mt][nt][0], acc[mt][nt][1], 0, false);
                w = __builtin_amdgcn_cvt_pk_fp8_f32(acc[mt][nt][2], acc[mt][nt][3], w, true);
                int col = wn * 64 + nt * 16 + l16;
#pragma unroll
                for (int r = 0; r < 4; r++)
                    escr[(wm * 64 + mt * 16 + quad * 4 + r) * 144 + col] = (char)(w >> (8 * r));
            }
        }
        __syncthreads();
        int row = tid >> 1;
        int t_in = (bx & 7) * 128 + row;
        char* dst = (which == 0) ? Q : K;
        size_t rowbase = ((size_t)((b_ * Hn + h_) * Tn + t_in)) * 128;
#pragma unroll
        for (int i = 0; i < 4; i++) {
            int c = (tid & 1) * 4 + i;
            int4 v = *(const int4*)(escr + row * 144 + c * 16);
            int cc = (which == 1) ? (c ^ (row & 7)) : c;
            *(int4*)(dst + rowbase + cc * 16) = v;
        }
    } else {
#pragma unroll
        for (int mt = 0; mt < 4; mt++) {
            int m_base = bx * 128 + wm * 64 + mt * 16 + quad * 4;
            int t0 = m_base & 1023;
#pragma unroll
            for (int nt = 0; nt < 4; nt++) {
                int e_ = wn * 64 + nt * 16 + l16;
                int kt_ = t0 >> 6, tc0 = t0 & 63;
                size_t off = ((((size_t)(b_ * Hn + h_) * 16 + kt_) * 128 + e_) << 6)
                           + ((((tc0 >> 3) ^ (e_ & 7)) << 3) | (tc0 & 7));
                ushort4 v4;
                v4.x = f2bf(acc[mt][nt][0]); v4.y = f2bf(acc[mt][nt][1]);
                v4.z = f2bf(acc[mt][nt][2]); v4.w = f2bf(acc[mt][nt][3]);
                *(ushort4*)(Vt + off) = v4;
            }
        }
    }
}

// ---------------- dispatch 2: flash attention + fused outproj ----------------
// XCD-aware remap: bh = id&63, t = id>>6, qb = t<4 ? t : 11-t.
// Same-bh blocks all have id%8 == bh%8 -> same XCD under round-robin -> that bh's
// K/V (384 KB) stays L2-resident, fetched from HBM once. Co-resident pair
// (id, id+256) has qb pairs (0,7),(1,6),(2,5),(3,4) -> every pair sums 18 iters.
__global__ __launch_bounds__(256, 2) void attn_kernel(
    const char* __restrict__ Q,               // fp8 [64][1024][128] plain
    const char* __restrict__ K,               // fp8 [64][1024][128] chunk swizzle c^(t&7)
    const unsigned short* __restrict__ Vt,    // bf16 [64][16][128][64] tiled+swizzled
    const unsigned long long* __restrict__ mbits, // [16][1024] transposed
    const unsigned short* __restrict__ wuF,   // [((h*4+ks)*8+nt)*64+lane][8]
    float* __restrict__ out)                  // [8192][128] fp32, bias-preset
{
    const int id   = blockIdx.x;
    const int bh   = id & 63;
    const int t_   = id >> 6;
    const int qb   = (t_ < 4) ? t_ : 11 - t_;
    const int wave = threadIdx.x >> 6;
    const int lane = threadIdx.x & 63;
    const int l16  = lane & 15;
    const int quad = lane >> 4;

    __shared__ __align__(16) char kbuf[2][64 * 128];            // 8 KB each
    __shared__ __align__(16) unsigned short vbuf[2][128 * 64];  // 16 KB each

    const char* Qb = Q  + (size_t)bh * Tn * Dn;
    const char* Kb = K  + (size_t)bh * Tn * Dn;
    const unsigned short* Vb = Vt + (size_t)bh * (16 * 128 * 64);

    const int blkkt = 2 * qb + 1;
    const int q0w   = qb * 128 + wave * 32;
    const int q0s[2] = { q0w, q0w + 16 };
    const int wkmax = (q0w + 31) >> 6;

    long qf[2][4];
#pragma unroll
    for (int st = 0; st < 2; st++)
#pragma unroll
        for (int ks = 0; ks < 4; ks++)
            qf[st][ks] = *(const long*)(Qb + (size_t)(q0s[st] + l16) * 128 + ks * 32 + quad * 8);

    bf16x8 ones;
#pragma unroll
    for (int j = 0; j < 8; j++) ones[j] = (short)0x3F80;

    f32x4 o[2][8];
#pragma unroll
    for (int st = 0; st < 2; st++)
#pragma unroll
        for (int et = 0; et < 8; et++) o[st][et] = (f32x4){0.f, 0.f, 0.f, 0.f};
    f32x4 lacc[2];
    lacc[0] = (f32x4){0.f, 0.f, 0.f, 0.f};
    lacc[1] = (f32x4){0.f, 0.f, 0.f, 0.f};

    const float SL = 0.12752041570284543f;  // 1/sqrt(128) * log2(e)

    const int idx0 = (l16 << 2) + ((quad & 1) << 7);
    const int idx1 = idx0 + 64;
    const bool hiQ = (quad >> 1) != 0;

#pragma unroll
    for (int i = 0; i < 2; i++) {
        int base = (wave * 2 + i) * 1024;
        gload_lds16b(Kb + base + lane * 16, &kbuf[0][base]);
    }
#pragma unroll
    for (int i = 0; i < 4; i++) {
        int base = (wave * 4 + i) * 512;
        gload_lds16(Vb + base + lane * 8, &vbuf[0][base]);
    }

    for (int kt = 0; kt <= blkkt; kt++) {
        const int cur = kt & 1;
        __syncthreads();

        if (kt < blkkt) {
            const char* Kg = Kb + (kt + 1) * (64 * 128);
            const unsigned short* Vg = Vb + (kt + 1) * (128 * 64);
#pragma unroll
            for (int i = 0; i < 2; i++) {
                int base = (wave * 2 + i) * 1024;
                gload_lds16b(Kg + base + lane * 16, &kbuf[cur ^ 1][base]);
            }
#pragma unroll
            for (int i = 0; i < 4; i++) {
                int base = (wave * 4 + i) * 512;
                gload_lds16(Vg + base + lane * 8, &vbuf[cur ^ 1][base]);
            }
        }

        if (kt <= wkmax) {
            unsigned long long mw[2];
            mw[0] = mbits[kt * Tn + q0s[0] + l16];
            mw[1] = mbits[kt * Tn + q0s[1] + l16];

            f32x4 s[2][4];
#pragma unroll
            for (int nt = 0; nt < 4; nt++) {
                int row = nt * 16 + l16;
                long a4[4];
#pragma unroll
                for (int ks = 0; ks < 4; ks++) {
                    int c = ks * 2 + (quad >> 1);
                    a4[ks] = *(const long*)(&kbuf[cur][row * 128 + (((c ^ (row & 7)) << 4) | ((quad & 1) << 3))]);
                }
#pragma unroll
                for (int st = 0; st < 2; st++) {
                    f32x4 c = {0.f, 0.f, 0.f, 0.f};
#pragma unroll
                    for (int ks = 0; ks < 4; ks++)
                        c = __builtin_amdgcn_mfma_f32_16x16x32_fp8_fp8(a4[ks], qf[st][ks], c, 0, 0, 0);
                    s[st][nt] = c;
                }
            }

            const int kc0 = kt * 64;
            bf16x8 pf[2][2];
#pragma unroll
            for (int st = 0; st < 2; st++) {
                const int qglob = q0s[st] + l16;
                int w[4][2];
#pragma unroll
                for (int nt = 0; nt < 4; nt++) {
                    float pv[4];
#pragma unroll
                    for (int r = 0; r < 4; r++) {
                        int bit = nt * 16 + quad * 4 + r;
                        bool live = ((mw[st] >> bit) & 1ULL) && (kc0 + bit <= qglob);
                        pv[r] = live ? __builtin_amdgcn_exp2f(s[st][nt][r] * SL) : 0.f;
                    }
                    w[nt][0] = pack_bf16_trunc(pv[0], pv[1]);
                    w[nt][1] = pack_bf16_trunc(pv[2], pv[3]);
                }
#pragma unroll
                for (int k2 = 0; k2 < 2; k2++) {
                    union { int i[4]; bf16x8 v; } u;
#pragma unroll
                    for (int d = 0; d < 4; d++) {
                        int idx = (d < 2) ? idx0 : idx1;
                        int va = __builtin_amdgcn_ds_bpermute(idx, w[2 * k2][d & 1]);
                        int vb = __builtin_amdgcn_ds_bpermute(idx, w[2 * k2 + 1][d & 1]);
                        u.i[d] = hiQ ? vb : va;
                    }
                    pf[st][k2] = u.v;
                }
            }

#pragma unroll
            for (int st = 0; st < 2; st++)
#pragma unroll
                for (int k2 = 0; k2 < 2; k2++)
                    lacc[st] = __builtin_amdgcn_mfma_f32_16x16x32_bf16(pf[st][k2], ones, lacc[st], 0, 0, 0);

#pragma unroll
            for (int et = 0; et < 8; et++) {
                int row = et * 16 + l16;
#pragma unroll
                for (int k2 = 0; k2 < 2; k2++) {
                    bf16x8 b = *(const bf16x8*)(&vbuf[cur][row * 64 + (((k2 * 4 + quad) ^ (l16 & 7)) << 3)]);
                    o[0][et] = __builtin_amdgcn_mfma_f32_16x16x32_bf16(pf[0][k2], b, o[0][et], 0, 0, 0);
                    o[1][et] = __builtin_amdgcn_mfma_f32_16x16x32_bf16(pf[1][k2], b, o[1][et], 0, 0, 0);
                }
            }
        }
    }

    // phase 2: degenerate rows (l == 0) attend uniformly over all mask==0 keys
    __syncthreads();
    {
        bool deg = false;
#pragma unroll
        for (int st = 0; st < 2; st++)
#pragma unroll
            for (int r = 0; r < 4; r++) deg |= (lacc[st][r] == 0.f);
        if (__ballot(deg) != 0ULL) {
            unsigned short* pb = (unsigned short*)((char*)kbuf + wave * 2304);  // 16 x 72 shorts
            unsigned short dsel[2][4];
#pragma unroll
            for (int st = 0; st < 2; st++)
#pragma unroll
                for (int r = 0; r < 4; r++)
                    dsel[st][r] = (lacc[st][r] == 0.f) ? (unsigned short)0x3F80 : (unsigned short)0;
            for (int kt = 0; kt < 16; kt++) {
#pragma unroll
                for (int st = 0; st < 2; st++) {
                    int qrow = q0s[st] + quad * 4;
                    unsigned long long mw2[4];
#pragma unroll
                    for (int r = 0; r < 4; r++) mw2[r] = mbits[kt * Tn + qrow + r];
#pragma unroll
                    for (int nt = 0; nt < 4; nt++) {
                        int bi = nt * 16 + l16;
#pragma unroll
                        for (int r = 0; r < 4; r++)
                            pb[(quad * 4 + r) * 72 + bi] = ((mw2[r] >> bi) & 1ULL) ? (unsigned short)0 : dsel[st][r];
                    }
                    bf16x8 pf[2];
#pragma unroll
                    for (int k2 = 0; k2 < 2; k2++)
                        pf[k2] = *(const bf16x8*)(&pb[l16 * 72 + k2 * 32 + quad * 8]);
#pragma unroll
                    for (int k2 = 0; k2 < 2; k2++)
                        lacc[st] = __builtin_amdgcn_mfma_f32_16x16x32_bf16(pf[k2], ones, lacc[st], 0, 0, 0);
                    const unsigned short* Vg = Vb + kt * (128 * 64);
#pragma unroll
                    for (int et = 0; et < 8; et++) {
#pragma unroll
                        for (int k2 = 0; k2 < 2; k2++) {
                            bf16x8 b = *(const bf16x8*)(Vg + (et * 16 + l16) * 64 + (((k2 * 4 + quad) ^ (l16 & 7)) << 3));
                            o[st][et] = __builtin_amdgcn_mfma_f32_16x16x32_bf16(pf[k2], b, o[st][et], 0, 0, 0);
                        }
                    }
                }
            }
        }
    }

    // fused output projection epilogue
    const int b_ = bh >> 3, h_ = bh & 7;
    const unsigned short* wf = wuF + (size_t)h_ * (4 * 8 * 64 * 8);
#pragma unroll
    for (int st = 0; st < 2; st++) {
        unsigned short* tile = (unsigned short*)((char*)vbuf + wave * 4608);  // 16 x 144 shorts
#pragma unroll
        for (int r = 0; r < 4; r++) {
            float inv = 1.f / lacc[st][r];
            int row = quad * 4 + r;
#pragma unroll
            for (int et = 0; et < 8; et++)
                tile[row * 144 + et * 16 + l16] = f2bf(o[st][et][r] * inv);
        }

        bf16x8 a4[4];
#pragma unroll
        for (int ks = 0; ks < 4; ks++)
            a4[ks] = *(const bf16x8*)(&tile[l16 * 144 + ks * 32 + quad * 8]);

        f32x4 acc2[8];
#pragma unroll
        for (int nt = 0; nt < 8; nt++) acc2[nt] = (f32x4){0.f, 0.f, 0.f, 0.f};
#pragma unroll
        for (int ks = 0; ks < 4; ks++) {
#pragma unroll
            for (int nt = 0; nt < 8; nt++) {
                bf16x8 b = *(const bf16x8*)(wf + ((size_t)(ks * 8 + nt) * 64 + lane) * 8);
                acc2[nt] = __builtin_amdgcn_mfma_f32_16x16x32_bf16(a4[ks], b, acc2[nt], 0, 0, 0);
            }
        }

#pragma unroll
        for (int nt = 0; nt < 8; nt++) {
            int n = nt * 16 + l16;
#pragma unroll
            for (int r = 0; r < 4; r++) {
                int q = q0s[st] + quad * 4 + r;
                atomicAdd(&out[(size_t)(b_ * Tn + q) * Dn + n], acc2[nt][r]);
            }
        }
    }
}

extern "C" void kernel_launch(void* const* d_in, const int* in_sizes, int n_in,
                              void* d_out, int out_size, void* d_ws, size_t ws_size,
                              hipStream_t stream) {
    const float* x   = (const float*)d_in[0];
    const int* mask  = (const int*)d_in[1];
    const float* Wk  = (const float*)d_in[2];
    const float* Wq  = (const float*)d_in[3];
    const float* Wv  = (const float*)d_in[4];
    const float* Wu  = (const float*)d_in[5];
    const float* bu  = (const float*)d_in[6];
    float* out = (float*)d_out;

    char* ws = (char*)d_ws;
    unsigned short* wuF = (unsigned short*)ws; ws += (size_t)128 * 1024 * 2;
    char* Qf  = ws; ws += (size_t)64 * 1024 * 128;
    char* Kf  = ws; ws += (size_t)64 * 1024 * 128;
    unsigned short* Vtw = (unsigned short*)ws; ws += (size_t)64 * 1024 * 128 * 2;
    unsigned long long* mb = (unsigned long long*)ws; ws += (size_t)1024 * 16 * 8;

    qkv_kernel<<<dim3(64, 24), 256, 0, stream>>>(x, Wq, Wk, Wv, Wu, mask, bu, out,
                                                 wuF, mb, Qf, Kf, Vtw);
    attn_kernel<<<dim3(512), 256, 0, stream>>>(Qf, Kf, Vtw, mb, wuF, out);
}